// Round 6
// baseline (130.460 us; speedup 1.0000x reference)
//
#include <hip/hip_runtime.h>

#define NB 32
#define N1 512
#define N2 512
#define DF 128
#define MW 256
#define KD 96
#define INVG 10.0f
#define GAM 0.1f
#define BARRIER 10000.0f
#define NREP 3

// ws layout (floats)
#define WS_NODE  0
#define WS_ABUF  (WS_NODE + NB*MW*KD)
#define WS_BBUF  (WS_ABUF + NB*MW*KD)

__device__ __forceinline__ bool feq(float a, float b) {
  return fabsf(a - b) <= 1e-4f * fmaxf(fabsf(a), fabsf(b)) + 1e-12f;
}

__device__ __forceinline__ float edgec(float s, float rdtv, float gub) {
  float d = s - 1.0f, ng = fminf(s, 0.f), ov = fmaxf(s - gub, 0.f);
  return rdtv*d*d + BARRIER*(ng*ng + ov*ov);
}

// ---------------- KA: fused rowmax + node costs (UNCHANGED, ~13.5 us) ----------------
__global__ __launch_bounds__(256) void k1_node(const float* __restrict__ s1f,
                                               const float* __restrict__ s2f,
                                               const float* __restrict__ tw,
                                               const float* __restrict__ glb_lb,
                                               const float* __restrict__ glb_ub,
                                               const float* __restrict__ t1,
                                               const float* __restrict__ t2,
                                               float* __restrict__ ws) {
  const int mb = blockIdx.x;
  const int b  = blockIdx.y;
  const int t  = threadIdx.x;
  const int lane = t & 63;
  const int wv = t >> 6;
  __shared__ float s1L[16*132];
  __shared__ float s2L[96*132];
  __shared__ float ndt[16*99];
  __shared__ float wtsL[16], lbL[16], ubL[16];
  __shared__ int   matchL[16];
  __shared__ float redm[8];

  {
    float m1 = -1e30f, m2 = -1e30f;
    for (int i = t; i < N1; i += 256) m1 = fmaxf(m1, t1[b*N1+i]);
    for (int i = t; i < N2; i += 256) m2 = fmaxf(m2, t2[b*N2+i]);
    #pragma unroll
    for (int o = 32; o; o >>= 1) {
      m1 = fmaxf(m1, __shfl_down(m1, o));
      m2 = fmaxf(m2, __shfl_down(m2, o));
    }
    if (lane == 0) { redm[wv] = m1; redm[4+wv] = m2; }
  }
  __syncthreads();
  const float T1 = fmaxf(fmaxf(redm[0], redm[1]), fmaxf(redm[2], redm[3]));
  const float T2 = fmaxf(fmaxf(redm[4], redm[5]), fmaxf(redm[6], redm[7]));
  const float lb0 = glb_lb[b*MW] * T2;
  const float ub0 = glb_ub[b*MW] * T2;
  float4* s1L4 = (float4*)s1L;
  float4* s2L4 = (float4*)s2L;
  const float4* s1f4 = (const float4*)(s1f + (size_t)b*N1*DF);
  const float4* s2f4 = (const float4*)(s2f + (size_t)b*N2*DF);

  {
    const int d32 = t & 31;
    const int k8  = t >> 5;
    #pragma unroll
    for (int kk = 0; kk < 12; kk++) {
      int k = k8 + 8*kk;
      float tau = lb0 + (ub0 - lb0) * (float)k * (1.0f/95.0f);
      float x = fminf(fmaxf(tau / T2, 0.f), 1.f) * (float)(N2-1);
      int i0 = (int)x; i0 = max(0, min(i0, N2-2));
      float w = x - (float)i0;
      float4 f0 = s2f4[(size_t)i0*32 + d32];
      float4 f1 = s2f4[(size_t)(i0+1)*32 + d32];
      float4 r;
      r.x = f0.x + (f1.x - f0.x)*w; r.y = f0.y + (f1.y - f0.y)*w;
      r.z = f0.z + (f1.z - f0.z)*w; r.w = f0.w + (f1.w - f0.w)*w;
      s2L4[k*33 + d32] = r;
    }
  }
  {
    const int smi = t >> 4, q = t & 15;
    const int m = mb*16 + smi;
    float twm = tw[b*MW + m];
    float x = fminf(fmaxf(twm / T1, 0.f), 1.f) * (float)(N1-1);
    int i0 = (int)x; i0 = max(0, min(i0, N1-2));
    float w = x - (float)i0;
    #pragma unroll
    for (int j = 0; j < 2; j++) {
      int d4 = q + 16*j;
      float4 f0 = s1f4[(size_t)i0*32 + d4];
      float4 f1 = s1f4[(size_t)(i0+1)*32 + d4];
      float4 r;
      r.x = f0.x + (f1.x - f0.x)*w; r.y = f0.y + (f1.y - f0.y)*w;
      r.z = f0.z + (f1.z - f0.z)*w; r.w = f0.w + (f1.w - f0.w)*w;
      s1L4[smi*33 + d4] = r;
    }
  }
  if (t < 16) {
    int m = mb*16 + t, g = b*MW + m;
    float twm = tw[g];
    float prev = (m > 0) ? tw[g-1] : twm;
    float next = (m < MW-1) ? tw[g+1] : twm;
    wtsL[t] = 0.5f*(next - prev);
    float lbm = glb_lb[g]*T2, ubm = glb_ub[g]*T2;
    lbL[t] = lbm; ubL[t] = ubm;
    matchL[t] = (feq(lbm, lb0) && feq(ubm, ub0)) ? 1 : 0;
  }
  __syncthreads();

  const int mi = t >> 4, kg = t & 15;
  const int m = mb*16 + mi;
  float acc[6];
  #pragma unroll
  for (int i = 0; i < 6; i++) acc[i] = 0.f;
  if (matchL[mi]) {
    for (int d4 = 0; d4 < 32; d4++) {
      float4 s1v = s1L4[mi*33 + d4];
      #pragma unroll
      for (int k12 = 0; k12 < 6; k12++) {
        int k = kg + 16*k12;
        float4 s2v = s2L4[k*33 + d4];
        float dx = s1v.x - s2v.x, dy = s1v.y - s2v.y;
        float dz = s1v.z - s2v.z, dw = s1v.w - s2v.w;
        acc[k12] += dx*dx + dy*dy + dz*dz + dw*dw;
      }
    }
  } else {
    const float lbm = lbL[mi], ubm = ubL[mi];
    int i0a[6]; float wa[6];
    #pragma unroll
    for (int k12 = 0; k12 < 6; k12++) {
      int k = kg + 16*k12;
      float tau = lbm + (ubm - lbm) * (float)k * (1.0f/95.0f);
      float x = fminf(fmaxf(tau / T2, 0.f), 1.f) * (float)(N2-1);
      int i0 = (int)x; i0 = max(0, min(i0, N2-2));
      i0a[k12] = i0; wa[k12] = x - (float)i0;
    }
    for (int d4 = 0; d4 < 32; d4++) {
      float4 s1v = s1L4[mi*33 + d4];
      #pragma unroll
      for (int k12 = 0; k12 < 6; k12++) {
        float4 f0 = s2f4[(size_t)i0a[k12]*32 + d4];
        float4 f1 = s2f4[(size_t)(i0a[k12]+1)*32 + d4];
        float w = wa[k12];
        float ax = f0.x + (f1.x - f0.x)*w, ay = f0.y + (f1.y - f0.y)*w;
        float az = f0.z + (f1.z - f0.z)*w, aw = f0.w + (f1.w - f0.w)*w;
        float dx = s1v.x - ax, dy = s1v.y - ay, dz = s1v.z - az, dw = s1v.w - aw;
        acc[k12] += dx*dx + dy*dy + dz*dz + dw*dw;
      }
    }
  }
  {
    const float wts = wtsL[mi];
    const float lbm = lbL[mi], ubm = ubL[mi];
    #pragma unroll
    for (int k12 = 0; k12 < 6; k12++) {
      int k = kg + 16*k12;
      float nodev = acc[k12] * wts;
      float tau = lbm + (ubm - lbm) * (float)k * (1.0f/95.0f);
      if (m == 0)    nodev += BARRIER * tau * tau;
      if (m == MW-1) { float dd = tau - T2; nodev += BARRIER * dd * dd; }
      ndt[mi*99 + k] = nodev;
    }
  }
  __syncthreads();
  float* nodeP = ws + WS_NODE + ((size_t)b*MW + mb*16)*KD;
  for (int idx = t; idx < 16*KD; idx += 256) {
    int mi2 = idx / KD, kv = idx - mi2*KD;
    nodeP[idx] = ndt[mi2*99 + kv];
  }
}

// ---------------- KB: DIAGNOSTIC — post-staging phases repeated NREP=3x ----------------
// Staging runs once; {rigor+scan+ok-branch+output} repeats (all idempotent,
// out rewritten identically). dur_delta vs R5 = 2 x (k2 - staging - launch).
__global__ __launch_bounds__(512) void k2_out(const float* __restrict__ tw,
                                              const float* __restrict__ glb_lb,
                                              const float* __restrict__ glb_ub,
                                              const float* __restrict__ reg_wt,
                                              const float* __restrict__ gubp,
                                              const float* __restrict__ t2,
                                              float* __restrict__ ws,
                                              float* __restrict__ out) {
  const int b = blockIdx.x;
  const int t = threadIdx.x;
  const int wv = t >> 6;          // 0..7
  const int lane = t & 63;
  __shared__ float ndL[MW*KD];   // 96 KB
  __shared__ float ndmL[MW];
  __shared__ float lbw[MW], ubw[MW], twv[MW];
  __shared__ float mir[2][KD];
  __shared__ float sred[32];
  __shared__ int skey[8];
  const float* __restrict__ nodeP = ws + WS_NODE + (size_t)b*MW*KD;

  // ---- one-time staging ----
  {
    const float4* np4 = (const float4*)nodeP;
    float4* nl4 = (float4*)ndL;
    #pragma unroll
    for (int it = 0; it < (MW*KD/4)/512; it++)
      nl4[t + 512*it] = np4[t + 512*it];
  }
  {
    float m2 = -1e30f;
    for (int i = t; i < N2; i += 512) m2 = fmaxf(m2, t2[b*N2+i]);
    #pragma unroll
    for (int o = 32; o; o >>= 1) m2 = fmaxf(m2, __shfl_down(m2, o));
    if (lane == 0) sred[wv] = m2;
  }
  __syncthreads();
  float T2;
  {
    float v = sred[0];
    #pragma unroll
    for (int w = 1; w < 8; w++) v = fmaxf(v, sred[w]);
    T2 = v;
  }
  for (int i = t; i < MW; i += 512) {
    lbw[i] = glb_lb[b*MW+i]*T2;
    ubw[i] = glb_ub[b*MW+i]*T2;
    twv[i] = tw[b*MW+i];
  }
  const float r = reg_wt[b];
  const float gub = gubp[b];
  __syncthreads();

  // ---- repeated phases ----
  #pragma unroll 1
  for (int rep = 0; rep < NREP; rep++) {
    __syncthreads();   // protect sred/skey reuse across reps

    // rigor checks
    const float lb0 = lbw[0], ub0 = ubw[0];
    const float g = (ub0 - lb0) * (1.0f/95.0f);
    bool keyok = true;
    float minE1 = 3e38f, minE2 = 3e38f, maxRdt = 0.f;
    for (int i = t; i < MW; i += 512)
      keyok = keyok && (lbw[i] == lb0) && (ubw[i] == ub0);
    for (int i = t; i < MW-1; i += 512) {
      float dtv = twv[i+1] - twv[i];
      if (!(dtv > 0.f)) keyok = false;
      else {
        float rdtv = r * dtv, sl = g / dtv;
        minE1 = fminf(minE1, fminf(edgec(sl, rdtv, gub), edgec(-sl, rdtv, gub)));
        minE2 = fminf(minE2, fminf(edgec(2.f*sl, rdtv, gub), edgec(-2.f*sl, rdtv, gub)));
        maxRdt = fmaxf(maxRdt, rdtv);
      }
    }

    // prefix-sum scan (waves 0-1)
    const bool actS = t < KD;
    const int k = actS ? t : (KD-1);
    float P = 0.f, mx = 0.f;
    if (t < 128) {
      const bool hasn = actS && (k < KD-1);
      float P2 = 0.f;
      #pragma unroll 8
      for (int m = 0; m < MW; m++) {
        float a  = ndL[m*KD + k];
        float bq = hasn ? ndL[m*KD + k + 1] : a;
        P += a; P2 += bq;
        mx = fmaxf(mx, fabsf(P - P2));
      }
      if (!actS) mx = 0.f;
    }
    {
      float wmx = mx, wE1 = minE1, wE2 = minE2, wR = maxRdt;
      #pragma unroll
      for (int o = 32; o; o >>= 1) {
        wmx = fmaxf(wmx, __shfl_xor(wmx, o));
        wE1 = fminf(wE1, __shfl_xor(wE1, o));
        wE2 = fminf(wE2, __shfl_xor(wE2, o));
        wR  = fmaxf(wR,  __shfl_xor(wR,  o));
      }
      int ka = __all(keyok ? 1 : 0);
      if (lane == 0) {
        sred[wv*4+0] = wmx; sred[wv*4+1] = wE1;
        sred[wv*4+2] = wE2; sred[wv*4+3] = wR;
        skey[wv] = ka;
      }
    }
    __syncthreads();
    float MX, E1, E2, RD; int KAll;
    {
      float a0 = sred[0], a1 = sred[1], a2 = sred[2], a3 = sred[3];
      int kk2 = skey[0];
      #pragma unroll
      for (int w = 1; w < 8; w++) {
        a0 = fmaxf(a0, sred[w*4+0]);
        a1 = fminf(a1, sred[w*4+1]);
        a2 = fminf(a2, sred[w*4+2]);
        a3 = fmaxf(a3, sred[w*4+3]);
        kk2 = kk2 && skey[w];
      }
      MX = a0; E1 = a1; E2 = a2; RD = a3; KAll = kk2;
    }
    const bool ok = KAll &&
                    (2.0f*MX   <= E1 - RD - 3.0f) &&
                    (190.0f*MX <= E2 - RD - 3.0f);

    if (ok) {
      // fast path
      __syncthreads();
      float s = actS ? P : 3e38f;
      float mnv = s;
      #pragma unroll
      for (int o = 32; o; o >>= 1) mnv = fminf(mnv, __shfl_xor(mnv, o));
      if (lane == 0) sred[wv] = mnv;
      __syncthreads();
      float mn;
      {
        float v = sred[0];
        #pragma unroll
        for (int w = 1; w < 8; w++) v = fminf(v, sred[w]);
        mn = v;
      }
      float w = actS ? __expf((mn - P) * INVG) : 0.f;
      float num = w * (float)k, den = w;
      #pragma unroll
      for (int o = 32; o; o >>= 1) {
        num += __shfl_xor(num, o);
        den += __shfl_xor(den, o);
      }
      if (lane == 0) { sred[8+wv] = num; sred[16+wv] = den; }
      __syncthreads();
      float nsum, dsum;
      {
        float n0 = sred[8], d0 = sred[16];
        #pragma unroll
        for (int w2 = 1; w2 < 8; w2++) { n0 += sred[8+w2]; d0 += sred[16+w2]; }
        nsum = n0; dsum = d0;
      }
      const float q = (nsum / dsum) * (1.0f/95.0f);
      for (int m = t; m < MW; m += 512)
        out[b*MW + m] = lbw[m] + (ubw[m] - lbw[m]) * q;
    } else {
      // generic fallback
      for (int i2 = t; i2 < MW; i2 += 512) {
        float mnv = 3e38f;
        for (int kk = 0; kk < KD; kk++) mnv = fminf(mnv, ndL[i2*KD + kk]);
        ndmL[i2] = mnv;
      }
      __syncthreads();

      if (t < 128) {
        const int dir = t >> 6;
        const bool act = lane < 48;
        const int k0i = 2*lane, k1i = 2*lane+1;
        const float frk0 = (float)k0i*(1.f/95.f), frk1 = (float)k1i*(1.f/95.f);
        float* __restrict__ outP = ws + (dir ? WS_BBUF : WS_ABUF) + (size_t)b*MW*KD;

        float a0 = 3e38f, a1 = 3e38f;
        {
          const int m0 = dir ? (MW-1) : 0;
          if (act) {
            a0 = ndL[m0*KD + k0i]; a1 = ndL[m0*KD + k1i];
            mir[dir][k0i] = a0; mir[dir][k1i] = a1;
            float2 o; o.x = dir ? 0.f : a0; o.y = dir ? 0.f : a1;
            *(float2*)&outP[(size_t)m0*KD + k0i] = o;
          }
        }
        float Blo;
        {
          float bl = act ? fminf(a0, a1) : 3e38f;
          #pragma unroll
          for (int o = 1; o < 64; o <<= 1) bl = fminf(bl, __shfl_xor(bl, o));
          Blo = bl;
        }
        float e00=3e38f,e0m=3e38f,e0p=3e38f,e10=3e38f,e1m=3e38f,e1p=3e38f;
        float eo0=3e38f, eo1=3e38f, eminmin=0.f;
        float cL1=__int_as_float(0x7fc00000), cU1=cL1, cL2=cL1, cU2=cL1, cdt=cL1;

        float pL1, pU1, pL2, pU2, pt1, pt2, pnd0=0.f, pnd1=0.f, pndm;
        {
          const int i0_ = dir ? (MW-2) : 0;
          pL1=lbw[i0_]; pU1=ubw[i0_]; pL2=lbw[i0_+1]; pU2=ubw[i0_+1];
          pt1=twv[i0_]; pt2=twv[i0_+1];
          const int mn_ = dir ? i0_ : (i0_+1);
          if (act) { float2 v = *(const float2*)&ndL[mn_*KD + k0i]; pnd0=v.x; pnd1=v.y; }
          pndm = ndmL[mn_];
        }

        for (int step = 0; step < MW-1; step++) {
          const float L1=pL1, U1=pU1, L2=pL2, U2=pU2;
          const float dt = pt2 - pt1;
          const float nd0=pnd0, nd1=pnd1, ndmn=pndm;
          {
            const int sn = (step+1 < MW-1) ? (step+1) : step;
            const int in_ = dir ? (MW-2-sn) : sn;
            pL1=lbw[in_]; pU1=ubw[in_]; pL2=lbw[in_+1]; pU2=ubw[in_+1];
            pt1=twv[in_]; pt2=twv[in_+1];
            const int mn_ = dir ? in_ : (in_+1);
            if (act) { float2 v = *(const float2*)&ndL[mn_*KD + k0i]; pnd0=v.x; pnd1=v.y; }
            pndm = ndmL[mn_];
          }
          const bool kc = !(feq(L1,cL1)&&feq(U1,cU1)&&feq(L2,cL2)&&feq(U2,cU2)&&feq(dt,cdt));
          if (kc) {
            cL1=L1; cU1=U1; cL2=L2; cU2=U2; cdt=dt;
            float bl = act ? fminf(mir[dir][k0i], mir[dir][k1i]) : 3e38f;
            #pragma unroll
            for (int o = 1; o < 64; o <<= 1) bl = fminf(bl, __shfl_xor(bl, o));
            Blo = bl;
            const float invdt = 1.f/dt, rdt = r*dt;
            const float my0 = dir ? (L1+(U1-L1)*frk0) : (L2+(U2-L2)*frk0);
            const float my1 = dir ? (L1+(U1-L1)*frk1) : (L2+(U2-L2)*frk1);
            e00=3e38f; e0m=3e38f; e0p=3e38f; e10=3e38f; e1m=3e38f; e1p=3e38f;
            eo0=3e38f; eo1=3e38f;
            float emn = 3e38f;
            for (int j = 0; j < KD; j++) {
              const float frj = (float)j*(1.f/95.f);
              const float oth = dir ? (L2+(U2-L2)*frj) : (L1+(U1-L1)*frj);
              const float sl0 = (dir ? (oth-my0) : (my0-oth))*invdt;
              const float sl1 = (dir ? (oth-my1) : (my1-oth))*invdt;
              float d0=sl0-1.f, g0=fminf(sl0,0.f), v0=fmaxf(sl0-gub,0.f);
              float ej0 = rdt*d0*d0 + BARRIER*(g0*g0+v0*v0);
              float d1=sl1-1.f, g1=fminf(sl1,0.f), v1=fmaxf(sl1-gub,0.f);
              float ej1 = rdt*d1*d1 + BARRIER*(g1*g1+v1*v1);
              emn = fminf(emn, fminf(ej0, ej1));
              if      (j == k0i-1) e0m = ej0;
              else if (j == k0i)   e00 = ej0;
              else if (j == k0i+1) e0p = ej0;
              else                 eo0 = fminf(eo0, ej0);
              if      (j == k1i-1) e1m = ej1;
              else if (j == k1i)   e10 = ej1;
              else if (j == k1i+1) e1p = ej1;
              else                 eo1 = fminf(eo1, ej1);
            }
            if (!act) emn = 3e38f;
            #pragma unroll
            for (int o = 1; o < 64; o <<= 1) emn = fminf(emn, __shfl_xor(emn, o));
            eminmin = emn;
          }
          const float a1p = __shfl_up(a1, 1);
          const float a0n = __shfl_down(a0, 1);
          const float x0m = fminf(a1p + e0m, 3e38f);
          const float x00 = fminf(a0  + e00, 3e38f);
          const float x0p = fminf(a1  + e0p, 3e38f);
          const float x1m = fminf(a0  + e1m, 3e38f);
          const float x10 = fminf(a1  + e10, 3e38f);
          const float x1p = fminf(a0n + e1p, 3e38f);
          float mn0 = fminf(fminf(x0m, x00), x0p);
          float mn1 = fminf(fminf(x1m, x10), x1p);
          float sum0 = __expf((mn0-x0m)*INVG) + __expf((mn0-x00)*INVG) + __expf((mn0-x0p)*INVG);
          float sum1 = __expf((mn1-x1m)*INVG) + __expf((mn1-x10)*INVG) + __expf((mn1-x1p)*INVG);
          const bool bad = act && ((Blo + eo0 - mn0 < 8.7f) || (Blo + eo1 - mn1 < 8.7f));
          if (__any((int)bad)) {
            const float invdt = 1.f/dt, rdt = r*dt;
            const float my0 = dir ? (L1+(U1-L1)*frk0) : (L2+(U2-L2)*frk0);
            const float my1 = dir ? (L1+(U1-L1)*frk1) : (L2+(U2-L2)*frk1);
            mn0 = 3e38f; mn1 = 3e38f;
            for (int j = 0; j < KD; j++) {
              const float sj = mir[dir][j];
              const float frj = (float)j*(1.f/95.f);
              const float oth = dir ? (L2+(U2-L2)*frj) : (L1+(U1-L1)*frj);
              const float sl0 = (dir ? (oth-my0) : (my0-oth))*invdt;
              const float sl1 = (dir ? (oth-my1) : (my1-oth))*invdt;
              float d0=sl0-1.f, g0=fminf(sl0,0.f), v0=fmaxf(sl0-gub,0.f);
              float ej0 = rdt*d0*d0 + BARRIER*(g0*g0+v0*v0);
              float d1=sl1-1.f, g1=fminf(sl1,0.f), v1=fmaxf(sl1-gub,0.f);
              float ej1 = rdt*d1*d1 + BARRIER*(g1*g1+v1*v1);
              mn0 = fminf(mn0, fminf(sj + ej0, 3e38f));
              mn1 = fminf(mn1, fminf(sj + ej1, 3e38f));
            }
            sum0 = 0.f; sum1 = 0.f;
            for (int j = 0; j < KD; j++) {
              const float sj = mir[dir][j];
              const float frj = (float)j*(1.f/95.f);
              const float oth = dir ? (L2+(U2-L2)*frj) : (L1+(U1-L1)*frj);
              const float sl0 = (dir ? (oth-my0) : (my0-oth))*invdt;
              const float sl1 = (dir ? (oth-my1) : (my1-oth))*invdt;
              float d0=sl0-1.f, g0=fminf(sl0,0.f), v0=fmaxf(sl0-gub,0.f);
              float ej0 = rdt*d0*d0 + BARRIER*(g0*g0+v0*v0);
              float d1=sl1-1.f, g1=fminf(sl1,0.f), v1=fmaxf(sl1-gub,0.f);
              float ej1 = rdt*d1*d1 + BARRIER*(g1*g1+v1*v1);
              sum0 += __expf((mn0 - fminf(sj + ej0, 3e38f))*INVG);
              sum1 += __expf((mn1 - fminf(sj + ej1, 3e38f))*INVG);
            }
          }
          const float sv0 = mn0 - GAM*__logf(sum0);
          const float sv1 = mn1 - GAM*__logf(sum1);
          const float na0 = nd0 + sv0, na1 = nd1 + sv1;
          const int ic = dir ? (MW-2-step) : step;
          const int mnode = dir ? ic : (ic+1);
          if (act) {
            mir[dir][k0i] = na0; mir[dir][k1i] = na1;
            float2 o; o.x = dir ? sv0 : na0; o.y = dir ? sv1 : na1;
            *(float2*)&outP[(size_t)mnode*KD + k0i] = o;
          }
          a0 = act ? na0 : 3e38f;
          a1 = act ? na1 : 3e38f;
          Blo += eminmin + ndmn - 0.4575f;
        }
      }

      __threadfence_block();
      __syncthreads();
      const float* __restrict__ Ab = ws + WS_ABUF + (size_t)b*MW*KD;
      const float* __restrict__ Bb = ws + WS_BBUF + (size_t)b*MW*KD;
      for (int m = t; m < MW; m += 512) {
        float mnv = 3e38f;
        for (int kk = 0; kk < KD; kk++)
          mnv = fminf(mnv, Ab[(size_t)m*KD+kk] + Bb[(size_t)m*KD+kk]);
        float num = 0.f, den = 0.f;
        for (int kk = 0; kk < KD; kk++) {
          float s = Ab[(size_t)m*KD+kk] + Bb[(size_t)m*KD+kk];
          float w = __expf((mnv - s) * INVG);
          num += w * (float)kk; den += w;
        }
        out[b*MW + m] = lbw[m] + (ubw[m] - lbw[m]) * (num/den) * (1.0f/95.0f);
      }
    }
    __syncthreads();
  }
}

extern "C" void kernel_launch(void* const* d_in, const int* in_sizes, int n_in,
                              void* d_out, int out_size, void* d_ws, size_t ws_size,
                              hipStream_t stream) {
  const float* s1f    = (const float*)d_in[0];
  const float* s2f    = (const float*)d_in[1];
  const float* regw   = (const float*)d_in[2];
  const float* glb_lb = (const float*)d_in[3];
  const float* glb_ub = (const float*)d_in[4];
  const float* gubp   = (const float*)d_in[5];
  const float* t1     = (const float*)d_in[6];
  const float* t2     = (const float*)d_in[7];
  const float* twp    = (const float*)d_in[8];
  float* ws  = (float*)d_ws;
  float* out = (float*)d_out;

  dim3 g1(16, NB);
  k1_node<<<g1, 256, 0, stream>>>(s1f, s2f, twp, glb_lb, glb_ub, t1, t2, ws);
  k2_out<<<NB, 512, 0, stream>>>(twp, glb_lb, glb_ub, regw, gubp, t2, ws, out);
}

// Round 7
// 107.992 us; speedup vs baseline: 1.2080x; 1.2080x over previous
//
#include <hip/hip_runtime.h>

#define NB 32
#define N1 512
#define N2 512
#define DF 128
#define MW 256
#define KD 96
#define INVG 10.0f
#define GAM 0.1f
#define BARRIER 10000.0f

// ws layout (floats)
#define WS_NODE  0
#define WS_ABUF  (WS_NODE + NB*MW*KD)
#define WS_BBUF  (WS_ABUF + NB*MW*KD)

__device__ __forceinline__ bool feq(float a, float b) {
  return fabsf(a - b) <= 1e-4f * fmaxf(fabsf(a), fabsf(b)) + 1e-12f;
}

__device__ __forceinline__ float edgec(float s, float rdtv, float gub) {
  float d = s - 1.0f, ng = fminf(s, 0.f), ov = fmaxf(s - gub, 0.f);
  return rdtv*d*d + BARRIER*(ng*ng + ov*ov);
}

// 1-lane whole-wave shifts via DPP (single VALU modifier, no LDS pipe).
// wave_shr:1 = 0x138 (lane i <- lane i-1, lane 0 -> 0)  == shfl_up(x,1)
// wave_shl:1 = 0x130 (lane i <- lane i+1, lane 63 -> 0) == shfl_down(x,1)
// Boundary lanes feed "x + 3e38" clamps that saturate identically for any
// x >= 0 (alphas are nonnegative), so results are bit-identical to shfl.
__device__ __forceinline__ float dpp_shr1(float x) {
  return __int_as_float(__builtin_amdgcn_update_dpp(
      0, __float_as_int(x), 0x138, 0xf, 0xf, true));
}
__device__ __forceinline__ float dpp_shl1(float x) {
  return __int_as_float(__builtin_amdgcn_update_dpp(
      0, __float_as_int(x), 0x130, 0xf, 0xf, true));
}

// ---------------- KA: fused rowmax + node costs (UNCHANGED, ~13.5 us) ----------------
__global__ __launch_bounds__(256) void k1_node(const float* __restrict__ s1f,
                                               const float* __restrict__ s2f,
                                               const float* __restrict__ tw,
                                               const float* __restrict__ glb_lb,
                                               const float* __restrict__ glb_ub,
                                               const float* __restrict__ t1,
                                               const float* __restrict__ t2,
                                               float* __restrict__ ws) {
  const int mb = blockIdx.x;
  const int b  = blockIdx.y;
  const int t  = threadIdx.x;
  const int lane = t & 63;
  const int wv = t >> 6;
  __shared__ float s1L[16*132];
  __shared__ float s2L[96*132];
  __shared__ float ndt[16*99];
  __shared__ float wtsL[16], lbL[16], ubL[16];
  __shared__ int   matchL[16];
  __shared__ float redm[8];

  {
    float m1 = -1e30f, m2 = -1e30f;
    for (int i = t; i < N1; i += 256) m1 = fmaxf(m1, t1[b*N1+i]);
    for (int i = t; i < N2; i += 256) m2 = fmaxf(m2, t2[b*N2+i]);
    #pragma unroll
    for (int o = 32; o; o >>= 1) {
      m1 = fmaxf(m1, __shfl_down(m1, o));
      m2 = fmaxf(m2, __shfl_down(m2, o));
    }
    if (lane == 0) { redm[wv] = m1; redm[4+wv] = m2; }
  }
  __syncthreads();
  const float T1 = fmaxf(fmaxf(redm[0], redm[1]), fmaxf(redm[2], redm[3]));
  const float T2 = fmaxf(fmaxf(redm[4], redm[5]), fmaxf(redm[6], redm[7]));
  const float lb0 = glb_lb[b*MW] * T2;
  const float ub0 = glb_ub[b*MW] * T2;
  float4* s1L4 = (float4*)s1L;
  float4* s2L4 = (float4*)s2L;
  const float4* s1f4 = (const float4*)(s1f + (size_t)b*N1*DF);
  const float4* s2f4 = (const float4*)(s2f + (size_t)b*N2*DF);

  {
    const int d32 = t & 31;
    const int k8  = t >> 5;
    #pragma unroll
    for (int kk = 0; kk < 12; kk++) {
      int k = k8 + 8*kk;
      float tau = lb0 + (ub0 - lb0) * (float)k * (1.0f/95.0f);
      float x = fminf(fmaxf(tau / T2, 0.f), 1.f) * (float)(N2-1);
      int i0 = (int)x; i0 = max(0, min(i0, N2-2));
      float w = x - (float)i0;
      float4 f0 = s2f4[(size_t)i0*32 + d32];
      float4 f1 = s2f4[(size_t)(i0+1)*32 + d32];
      float4 r;
      r.x = f0.x + (f1.x - f0.x)*w; r.y = f0.y + (f1.y - f0.y)*w;
      r.z = f0.z + (f1.z - f0.z)*w; r.w = f0.w + (f1.w - f0.w)*w;
      s2L4[k*33 + d32] = r;
    }
  }
  {
    const int smi = t >> 4, q = t & 15;
    const int m = mb*16 + smi;
    float twm = tw[b*MW + m];
    float x = fminf(fmaxf(twm / T1, 0.f), 1.f) * (float)(N1-1);
    int i0 = (int)x; i0 = max(0, min(i0, N1-2));
    float w = x - (float)i0;
    #pragma unroll
    for (int j = 0; j < 2; j++) {
      int d4 = q + 16*j;
      float4 f0 = s1f4[(size_t)i0*32 + d4];
      float4 f1 = s1f4[(size_t)(i0+1)*32 + d4];
      float4 r;
      r.x = f0.x + (f1.x - f0.x)*w; r.y = f0.y + (f1.y - f0.y)*w;
      r.z = f0.z + (f1.z - f0.z)*w; r.w = f0.w + (f1.w - f0.w)*w;
      s1L4[smi*33 + d4] = r;
    }
  }
  if (t < 16) {
    int m = mb*16 + t, g = b*MW + m;
    float twm = tw[g];
    float prev = (m > 0) ? tw[g-1] : twm;
    float next = (m < MW-1) ? tw[g+1] : twm;
    wtsL[t] = 0.5f*(next - prev);
    float lbm = glb_lb[g]*T2, ubm = glb_ub[g]*T2;
    lbL[t] = lbm; ubL[t] = ubm;
    matchL[t] = (feq(lbm, lb0) && feq(ubm, ub0)) ? 1 : 0;
  }
  __syncthreads();

  const int mi = t >> 4, kg = t & 15;
  const int m = mb*16 + mi;
  float acc[6];
  #pragma unroll
  for (int i = 0; i < 6; i++) acc[i] = 0.f;
  if (matchL[mi]) {
    for (int d4 = 0; d4 < 32; d4++) {
      float4 s1v = s1L4[mi*33 + d4];
      #pragma unroll
      for (int k12 = 0; k12 < 6; k12++) {
        int k = kg + 16*k12;
        float4 s2v = s2L4[k*33 + d4];
        float dx = s1v.x - s2v.x, dy = s1v.y - s2v.y;
        float dz = s1v.z - s2v.z, dw = s1v.w - s2v.w;
        acc[k12] += dx*dx + dy*dy + dz*dz + dw*dw;
      }
    }
  } else {
    const float lbm = lbL[mi], ubm = ubL[mi];
    int i0a[6]; float wa[6];
    #pragma unroll
    for (int k12 = 0; k12 < 6; k12++) {
      int k = kg + 16*k12;
      float tau = lbm + (ubm - lbm) * (float)k * (1.0f/95.0f);
      float x = fminf(fmaxf(tau / T2, 0.f), 1.f) * (float)(N2-1);
      int i0 = (int)x; i0 = max(0, min(i0, N2-2));
      i0a[k12] = i0; wa[k12] = x - (float)i0;
    }
    for (int d4 = 0; d4 < 32; d4++) {
      float4 s1v = s1L4[mi*33 + d4];
      #pragma unroll
      for (int k12 = 0; k12 < 6; k12++) {
        float4 f0 = s2f4[(size_t)i0a[k12]*32 + d4];
        float4 f1 = s2f4[(size_t)(i0a[k12]+1)*32 + d4];
        float w = wa[k12];
        float ax = f0.x + (f1.x - f0.x)*w, ay = f0.y + (f1.y - f0.y)*w;
        float az = f0.z + (f1.z - f0.z)*w, aw = f0.w + (f1.w - f0.w)*w;
        float dx = s1v.x - ax, dy = s1v.y - ay, dz = s1v.z - az, dw = s1v.w - aw;
        acc[k12] += dx*dx + dy*dy + dz*dz + dw*dw;
      }
    }
  }
  {
    const float wts = wtsL[mi];
    const float lbm = lbL[mi], ubm = ubL[mi];
    #pragma unroll
    for (int k12 = 0; k12 < 6; k12++) {
      int k = kg + 16*k12;
      float nodev = acc[k12] * wts;
      float tau = lbm + (ubm - lbm) * (float)k * (1.0f/95.0f);
      if (m == 0)    nodev += BARRIER * tau * tau;
      if (m == MW-1) { float dd = tau - T2; nodev += BARRIER * dd * dd; }
      ndt[mi*99 + k] = nodev;
    }
  }
  __syncthreads();
  float* nodeP = ws + WS_NODE + ((size_t)b*MW + mb*16)*KD;
  for (int idx = t; idx < 16*KD; idx += 256) {
    int mi2 = idx / KD, kv = idx - mi2*KD;
    nodeP[idx] = ndt[mi2*99 + kv];
  }
}

// ---------------- KB: fused DP + readout (512 threads; DPP shuffles in DP) ----------------
// R6 probe: fallback DP is the live path (~11.1 us/rep steady-state ~105 cyc/step).
// This round: replace the two per-step ds_bpermute shuffles on the loop-carried
// dependency with wave_shr:1 / wave_shl:1 DPP (bit-identical values).
__global__ __launch_bounds__(512) void k2_out(const float* __restrict__ tw,
                                              const float* __restrict__ glb_lb,
                                              const float* __restrict__ glb_ub,
                                              const float* __restrict__ reg_wt,
                                              const float* __restrict__ gubp,
                                              const float* __restrict__ t2,
                                              float* __restrict__ ws,
                                              float* __restrict__ out) {
  const int b = blockIdx.x;
  const int t = threadIdx.x;
  const int wv = t >> 6;          // 0..7
  const int lane = t & 63;
  __shared__ float ndL[MW*KD];   // 96 KB
  __shared__ float ndmL[MW];
  __shared__ float lbw[MW], ubw[MW], twv[MW];
  __shared__ float mir[2][KD];
  __shared__ float sred[32];
  __shared__ int skey[8];
  const float* __restrict__ nodeP = ws + WS_NODE + (size_t)b*MW*KD;

  // stage node -> LDS
  {
    const float4* np4 = (const float4*)nodeP;
    float4* nl4 = (float4*)ndL;
    #pragma unroll
    for (int it = 0; it < (MW*KD/4)/512; it++)
      nl4[t + 512*it] = np4[t + 512*it];
  }
  // T2 = max t2[b]
  {
    float m2 = -1e30f;
    for (int i = t; i < N2; i += 512) m2 = fmaxf(m2, t2[b*N2+i]);
    #pragma unroll
    for (int o = 32; o; o >>= 1) m2 = fmaxf(m2, __shfl_down(m2, o));
    if (lane == 0) sred[wv] = m2;
  }
  __syncthreads();
  float T2;
  {
    float v = sred[0];
    #pragma unroll
    for (int w = 1; w < 8; w++) v = fmaxf(v, sred[w]);
    T2 = v;
  }
  for (int i = t; i < MW; i += 512) {
    lbw[i] = glb_lb[b*MW+i]*T2;
    ubw[i] = glb_ub[b*MW+i]*T2;
    twv[i] = tw[b*MW+i];
  }
  const float r = reg_wt[b];
  const float gub = gubp[b];
  __syncthreads();

  // ---- rigor checks ----
  const float lb0 = lbw[0], ub0 = ubw[0];
  const float g = (ub0 - lb0) * (1.0f/95.0f);
  bool keyok = true;
  float minE1 = 3e38f, minE2 = 3e38f, maxRdt = 0.f;
  for (int i = t; i < MW; i += 512)
    keyok = keyok && (lbw[i] == lb0) && (ubw[i] == ub0);
  for (int i = t; i < MW-1; i += 512) {
    float dtv = twv[i+1] - twv[i];
    if (!(dtv > 0.f)) keyok = false;
    else {
      float rdtv = r * dtv, sl = g / dtv;
      minE1 = fminf(minE1, fminf(edgec(sl, rdtv, gub), edgec(-sl, rdtv, gub)));
      minE2 = fminf(minE2, fminf(edgec(2.f*sl, rdtv, gub), edgec(-2.f*sl, rdtv, gub)));
      maxRdt = fmaxf(maxRdt, rdtv);
    }
  }

  // ---- prefix-sum scan (waves 0-1) ----
  const bool actS = t < KD;
  const int k = actS ? t : (KD-1);
  float P = 0.f, mx = 0.f;
  if (t < 128) {
    const bool hasn = actS && (k < KD-1);
    float P2 = 0.f;
    #pragma unroll 8
    for (int m = 0; m < MW; m++) {
      float a  = ndL[m*KD + k];
      float bq = hasn ? ndL[m*KD + k + 1] : a;
      P += a; P2 += bq;
      mx = fmaxf(mx, fabsf(P - P2));
    }
    if (!actS) mx = 0.f;
  }
  {
    float wmx = mx, wE1 = minE1, wE2 = minE2, wR = maxRdt;
    #pragma unroll
    for (int o = 32; o; o >>= 1) {
      wmx = fmaxf(wmx, __shfl_xor(wmx, o));
      wE1 = fminf(wE1, __shfl_xor(wE1, o));
      wE2 = fminf(wE2, __shfl_xor(wE2, o));
      wR  = fmaxf(wR,  __shfl_xor(wR,  o));
    }
    int ka = __all(keyok ? 1 : 0);
    if (lane == 0) {
      sred[wv*4+0] = wmx; sred[wv*4+1] = wE1;
      sred[wv*4+2] = wE2; sred[wv*4+3] = wR;
      skey[wv] = ka;
    }
  }
  __syncthreads();
  float MX, E1, E2, RD; int KAll;
  {
    float a0 = sred[0], a1 = sred[1], a2 = sred[2], a3 = sred[3];
    int kk2 = skey[0];
    #pragma unroll
    for (int w = 1; w < 8; w++) {
      a0 = fmaxf(a0, sred[w*4+0]);
      a1 = fminf(a1, sred[w*4+1]);
      a2 = fminf(a2, sred[w*4+2]);
      a3 = fmaxf(a3, sred[w*4+3]);
      kk2 = kk2 && skey[w];
    }
    MX = a0; E1 = a1; E2 = a2; RD = a3; KAll = kk2;
  }
  const bool ok = KAll &&
                  (2.0f*MX   <= E1 - RD - 3.0f) &&
                  (190.0f*MX <= E2 - RD - 3.0f);

  if (ok) {
    // fast path
    __syncthreads();
    float s = actS ? P : 3e38f;
    float mnv = s;
    #pragma unroll
    for (int o = 32; o; o >>= 1) mnv = fminf(mnv, __shfl_xor(mnv, o));
    if (lane == 0) sred[wv] = mnv;
    __syncthreads();
    float mn;
    {
      float v = sred[0];
      #pragma unroll
      for (int w = 1; w < 8; w++) v = fminf(v, sred[w]);
      mn = v;
    }
    float w = actS ? __expf((mn - P) * INVG) : 0.f;
    float num = w * (float)k, den = w;
    #pragma unroll
    for (int o = 32; o; o >>= 1) {
      num += __shfl_xor(num, o);
      den += __shfl_xor(den, o);
    }
    if (lane == 0) { sred[8+wv] = num; sred[16+wv] = den; }
    __syncthreads();
    float nsum, dsum;
    {
      float n0 = sred[8], d0 = sred[16];
      #pragma unroll
      for (int w2 = 1; w2 < 8; w2++) { n0 += sred[8+w2]; d0 += sred[16+w2]; }
      nsum = n0; dsum = d0;
    }
    const float q = (nsum / dsum) * (1.0f/95.0f);
    for (int m = t; m < MW; m += 512)
      out[b*MW + m] = lbw[m] + (ubw[m] - lbw[m]) * q;
    return;
  }

  // ---------- generic fallback: sequential register DP (waves 0-1) ----------
  {
    for (int i2 = t; i2 < MW; i2 += 512) {
      float mnv = 3e38f;
      for (int kk = 0; kk < KD; kk++) mnv = fminf(mnv, ndL[i2*KD + kk]);
      ndmL[i2] = mnv;
    }
    __syncthreads();

    if (t < 128) {
      const int dir = t >> 6;
      const bool act = lane < 48;
      const int k0i = 2*lane, k1i = 2*lane+1;
      const float frk0 = (float)k0i*(1.f/95.f), frk1 = (float)k1i*(1.f/95.f);
      float* __restrict__ outP = ws + (dir ? WS_BBUF : WS_ABUF) + (size_t)b*MW*KD;

      float a0 = 3e38f, a1 = 3e38f;
      {
        const int m0 = dir ? (MW-1) : 0;
        if (act) {
          a0 = ndL[m0*KD + k0i]; a1 = ndL[m0*KD + k1i];
          mir[dir][k0i] = a0; mir[dir][k1i] = a1;
          float2 o; o.x = dir ? 0.f : a0; o.y = dir ? 0.f : a1;
          *(float2*)&outP[(size_t)m0*KD + k0i] = o;
        }
      }
      float Blo;
      {
        float bl = act ? fminf(a0, a1) : 3e38f;
        #pragma unroll
        for (int o = 1; o < 64; o <<= 1) bl = fminf(bl, __shfl_xor(bl, o));
        Blo = bl;
      }
      float e00=3e38f,e0m=3e38f,e0p=3e38f,e10=3e38f,e1m=3e38f,e1p=3e38f;
      float eo0=3e38f, eo1=3e38f, eminmin=0.f;
      float cL1=__int_as_float(0x7fc00000), cU1=cL1, cL2=cL1, cU2=cL1, cdt=cL1;

      float pL1, pU1, pL2, pU2, pt1, pt2, pnd0=0.f, pnd1=0.f, pndm;
      {
        const int i0_ = dir ? (MW-2) : 0;
        pL1=lbw[i0_]; pU1=ubw[i0_]; pL2=lbw[i0_+1]; pU2=ubw[i0_+1];
        pt1=twv[i0_]; pt2=twv[i0_+1];
        const int mn_ = dir ? i0_ : (i0_+1);
        if (act) { float2 v = *(const float2*)&ndL[mn_*KD + k0i]; pnd0=v.x; pnd1=v.y; }
        pndm = ndmL[mn_];
      }

      for (int step = 0; step < MW-1; step++) {
        const float L1=pL1, U1=pU1, L2=pL2, U2=pU2;
        const float dt = pt2 - pt1;
        const float nd0=pnd0, nd1=pnd1, ndmn=pndm;
        {
          const int sn = (step+1 < MW-1) ? (step+1) : step;
          const int in_ = dir ? (MW-2-sn) : sn;
          pL1=lbw[in_]; pU1=ubw[in_]; pL2=lbw[in_+1]; pU2=ubw[in_+1];
          pt1=twv[in_]; pt2=twv[in_+1];
          const int mn_ = dir ? in_ : (in_+1);
          if (act) { float2 v = *(const float2*)&ndL[mn_*KD + k0i]; pnd0=v.x; pnd1=v.y; }
          pndm = ndmL[mn_];
        }
        const bool kc = !(feq(L1,cL1)&&feq(U1,cU1)&&feq(L2,cL2)&&feq(U2,cU2)&&feq(dt,cdt));
        if (kc) {
          cL1=L1; cU1=U1; cL2=L2; cU2=U2; cdt=dt;
          float bl = act ? fminf(mir[dir][k0i], mir[dir][k1i]) : 3e38f;
          #pragma unroll
          for (int o = 1; o < 64; o <<= 1) bl = fminf(bl, __shfl_xor(bl, o));
          Blo = bl;
          const float invdt = 1.f/dt, rdt = r*dt;
          const float my0 = dir ? (L1+(U1-L1)*frk0) : (L2+(U2-L2)*frk0);
          const float my1 = dir ? (L1+(U1-L1)*frk1) : (L2+(U2-L2)*frk1);
          e00=3e38f; e0m=3e38f; e0p=3e38f; e10=3e38f; e1m=3e38f; e1p=3e38f;
          eo0=3e38f; eo1=3e38f;
          float emn = 3e38f;
          for (int j = 0; j < KD; j++) {
            const float frj = (float)j*(1.f/95.f);
            const float oth = dir ? (L2+(U2-L2)*frj) : (L1+(U1-L1)*frj);
            const float sl0 = (dir ? (oth-my0) : (my0-oth))*invdt;
            const float sl1 = (dir ? (oth-my1) : (my1-oth))*invdt;
            float d0=sl0-1.f, g0=fminf(sl0,0.f), v0=fmaxf(sl0-gub,0.f);
            float ej0 = rdt*d0*d0 + BARRIER*(g0*g0+v0*v0);
            float d1=sl1-1.f, g1=fminf(sl1,0.f), v1=fmaxf(sl1-gub,0.f);
            float ej1 = rdt*d1*d1 + BARRIER*(g1*g1+v1*v1);
            emn = fminf(emn, fminf(ej0, ej1));
            if      (j == k0i-1) e0m = ej0;
            else if (j == k0i)   e00 = ej0;
            else if (j == k0i+1) e0p = ej0;
            else                 eo0 = fminf(eo0, ej0);
            if      (j == k1i-1) e1m = ej1;
            else if (j == k1i)   e10 = ej1;
            else if (j == k1i+1) e1p = ej1;
            else                 eo1 = fminf(eo1, ej1);
          }
          if (!act) emn = 3e38f;
          #pragma unroll
          for (int o = 1; o < 64; o <<= 1) emn = fminf(emn, __shfl_xor(emn, o));
          eminmin = emn;
        }
        const float a1p = dpp_shr1(a1);   // == __shfl_up(a1,1); lane0 -> 0, dead via e0m=3e38 clamp
        const float a0n = dpp_shl1(a0);   // == __shfl_down(a0,1); lane63 -> 0, dead (act<48)
        const float x0m = fminf(a1p + e0m, 3e38f);
        const float x00 = fminf(a0  + e00, 3e38f);
        const float x0p = fminf(a1  + e0p, 3e38f);
        const float x1m = fminf(a0  + e1m, 3e38f);
        const float x10 = fminf(a1  + e10, 3e38f);
        const float x1p = fminf(a0n + e1p, 3e38f);
        float mn0 = fminf(fminf(x0m, x00), x0p);
        float mn1 = fminf(fminf(x1m, x10), x1p);
        float sum0 = __expf((mn0-x0m)*INVG) + __expf((mn0-x00)*INVG) + __expf((mn0-x0p)*INVG);
        float sum1 = __expf((mn1-x1m)*INVG) + __expf((mn1-x10)*INVG) + __expf((mn1-x1p)*INVG);
        const bool bad = act && ((Blo + eo0 - mn0 < 8.7f) || (Blo + eo1 - mn1 < 8.7f));
        if (__any((int)bad)) {
          const float invdt = 1.f/dt, rdt = r*dt;
          const float my0 = dir ? (L1+(U1-L1)*frk0) : (L2+(U2-L2)*frk0);
          const float my1 = dir ? (L1+(U1-L1)*frk1) : (L2+(U2-L2)*frk1);
          mn0 = 3e38f; mn1 = 3e38f;
          for (int j = 0; j < KD; j++) {
            const float sj = mir[dir][j];
            const float frj = (float)j*(1.f/95.f);
            const float oth = dir ? (L2+(U2-L2)*frj) : (L1+(U1-L1)*frj);
            const float sl0 = (dir ? (oth-my0) : (my0-oth))*invdt;
            const float sl1 = (dir ? (oth-my1) : (my1-oth))*invdt;
            float d0=sl0-1.f, g0=fminf(sl0,0.f), v0=fmaxf(sl0-gub,0.f);
            float ej0 = rdt*d0*d0 + BARRIER*(g0*g0+v0*v0);
            float d1=sl1-1.f, g1=fminf(sl1,0.f), v1=fmaxf(sl1-gub,0.f);
            float ej1 = rdt*d1*d1 + BARRIER*(g1*g1+v1*v1);
            mn0 = fminf(mn0, fminf(sj + ej0, 3e38f));
            mn1 = fminf(mn1, fminf(sj + ej1, 3e38f));
          }
          sum0 = 0.f; sum1 = 0.f;
          for (int j = 0; j < KD; j++) {
            const float sj = mir[dir][j];
            const float frj = (float)j*(1.f/95.f);
            const float oth = dir ? (L2+(U2-L2)*frj) : (L1+(U1-L1)*frj);
            const float sl0 = (dir ? (oth-my0) : (my0-oth))*invdt;
            const float sl1 = (dir ? (oth-my1) : (my1-oth))*invdt;
            float d0=sl0-1.f, g0=fminf(sl0,0.f), v0=fmaxf(sl0-gub,0.f);
            float ej0 = rdt*d0*d0 + BARRIER*(g0*g0+v0*v0);
            float d1=sl1-1.f, g1=fminf(sl1,0.f), v1=fmaxf(sl1-gub,0.f);
            float ej1 = rdt*d1*d1 + BARRIER*(g1*g1+v1*v1);
            sum0 += __expf((mn0 - fminf(sj + ej0, 3e38f))*INVG);
            sum1 += __expf((mn1 - fminf(sj + ej1, 3e38f))*INVG);
          }
        }
        const float sv0 = mn0 - GAM*__logf(sum0);
        const float sv1 = mn1 - GAM*__logf(sum1);
        const float na0 = nd0 + sv0, na1 = nd1 + sv1;
        const int ic = dir ? (MW-2-step) : step;
        const int mnode = dir ? ic : (ic+1);
        if (act) {
          mir[dir][k0i] = na0; mir[dir][k1i] = na1;
          float2 o; o.x = dir ? sv0 : na0; o.y = dir ? sv1 : na1;
          *(float2*)&outP[(size_t)mnode*KD + k0i] = o;
        }
        a0 = act ? na0 : 3e38f;
        a1 = act ? na1 : 3e38f;
        Blo += eminmin + ndmn - 0.4575f;
      }
    }

    // in-block readout (fallback only)
    __threadfence_block();
    __syncthreads();
    const float* __restrict__ Ab = ws + WS_ABUF + (size_t)b*MW*KD;
    const float* __restrict__ Bb = ws + WS_BBUF + (size_t)b*MW*KD;
    for (int m = t; m < MW; m += 512) {
      float mnv = 3e38f;
      for (int kk = 0; kk < KD; kk++)
        mnv = fminf(mnv, Ab[(size_t)m*KD+kk] + Bb[(size_t)m*KD+kk]);
      float num = 0.f, den = 0.f;
      for (int kk = 0; kk < KD; kk++) {
        float s = Ab[(size_t)m*KD+kk] + Bb[(size_t)m*KD+kk];
        float w = __expf((mnv - s) * INVG);
        num += w * (float)kk; den += w;
      }
      out[b*MW + m] = lbw[m] + (ubw[m] - lbw[m]) * (num/den) * (1.0f/95.0f);
    }
  }
}

extern "C" void kernel_launch(void* const* d_in, const int* in_sizes, int n_in,
                              void* d_out, int out_size, void* d_ws, size_t ws_size,
                              hipStream_t stream) {
  const float* s1f    = (const float*)d_in[0];
  const float* s2f    = (const float*)d_in[1];
  const float* regw   = (const float*)d_in[2];
  const float* glb_lb = (const float*)d_in[3];
  const float* glb_ub = (const float*)d_in[4];
  const float* gubp   = (const float*)d_in[5];
  const float* t1     = (const float*)d_in[6];
  const float* t2     = (const float*)d_in[7];
  const float* twp    = (const float*)d_in[8];
  float* ws  = (float*)d_ws;
  float* out = (float*)d_out;

  dim3 g1(16, NB);
  k1_node<<<g1, 256, 0, stream>>>(s1f, s2f, twp, glb_lb, glb_ub, t1, t2, ws);
  k2_out<<<NB, 512, 0, stream>>>(twp, glb_lb, glb_ub, regw, gubp, t2, ws, out);
}

// Round 8
// 106.464 us; speedup vs baseline: 1.2254x; 1.0144x over previous
//
#include <hip/hip_runtime.h>

#define NB 32
#define N1 512
#define N2 512
#define DF 128
#define MW 256
#define KD 96
#define INVG 10.0f
#define GAM 0.1f
#define BARRIER 10000.0f

// ws layout (floats)
#define WS_NODE  0
#define WS_ABUF  (WS_NODE + NB*MW*KD)
#define WS_BBUF  (WS_ABUF + NB*MW*KD)

__device__ __forceinline__ bool feq(float a, float b) {
  return fabsf(a - b) <= 1e-4f * fmaxf(fabsf(a), fabsf(b)) + 1e-12f;
}

__device__ __forceinline__ float edgec(float s, float rdtv, float gub) {
  float d = s - 1.0f, ng = fminf(s, 0.f), ov = fmaxf(s - gub, 0.f);
  return rdtv*d*d + BARRIER*(ng*ng + ov*ov);
}

// 1-lane whole-wave shifts via DPP (neutral vs shfl per R7; kept).
__device__ __forceinline__ float dpp_shr1(float x) {
  return __int_as_float(__builtin_amdgcn_update_dpp(
      0, __float_as_int(x), 0x138, 0xf, 0xf, true));
}
__device__ __forceinline__ float dpp_shl1(float x) {
  return __int_as_float(__builtin_amdgcn_update_dpp(
      0, __float_as_int(x), 0x130, 0xf, 0xf, true));
}

// ---------------- KA: fused rowmax + node costs ----------------
// R8: 2m x 3k per-thread tile — 5 LDS-read instrs per d4 per wave (was 7).
// Per-(m,k) accumulation order over d unchanged -> node bit-identical.
__global__ __launch_bounds__(256) void k1_node(const float* __restrict__ s1f,
                                               const float* __restrict__ s2f,
                                               const float* __restrict__ tw,
                                               const float* __restrict__ glb_lb,
                                               const float* __restrict__ glb_ub,
                                               const float* __restrict__ t1,
                                               const float* __restrict__ t2,
                                               float* __restrict__ ws) {
  const int mb = blockIdx.x;
  const int b  = blockIdx.y;
  const int t  = threadIdx.x;
  const int lane = t & 63;
  const int wv = t >> 6;
  __shared__ float s1L[16*132];
  __shared__ float s2L[96*132];
  __shared__ float ndt[16*99];
  __shared__ float wtsL[16], lbL[16], ubL[16];
  __shared__ int   matchL[16];
  __shared__ float redm[8];

  {
    float m1 = -1e30f, m2 = -1e30f;
    for (int i = t; i < N1; i += 256) m1 = fmaxf(m1, t1[b*N1+i]);
    for (int i = t; i < N2; i += 256) m2 = fmaxf(m2, t2[b*N2+i]);
    #pragma unroll
    for (int o = 32; o; o >>= 1) {
      m1 = fmaxf(m1, __shfl_down(m1, o));
      m2 = fmaxf(m2, __shfl_down(m2, o));
    }
    if (lane == 0) { redm[wv] = m1; redm[4+wv] = m2; }
  }
  __syncthreads();
  const float T1 = fmaxf(fmaxf(redm[0], redm[1]), fmaxf(redm[2], redm[3]));
  const float T2 = fmaxf(fmaxf(redm[4], redm[5]), fmaxf(redm[6], redm[7]));
  const float lb0 = glb_lb[b*MW] * T2;
  const float ub0 = glb_ub[b*MW] * T2;
  float4* s1L4 = (float4*)s1L;
  float4* s2L4 = (float4*)s2L;
  const float4* s1f4 = (const float4*)(s1f + (size_t)b*N1*DF);
  const float4* s2f4 = (const float4*)(s2f + (size_t)b*N2*DF);

  {
    const int d32 = t & 31;
    const int k8  = t >> 5;
    #pragma unroll
    for (int kk = 0; kk < 12; kk++) {
      int k = k8 + 8*kk;
      float tau = lb0 + (ub0 - lb0) * (float)k * (1.0f/95.0f);
      float x = fminf(fmaxf(tau / T2, 0.f), 1.f) * (float)(N2-1);
      int i0 = (int)x; i0 = max(0, min(i0, N2-2));
      float w = x - (float)i0;
      float4 f0 = s2f4[(size_t)i0*32 + d32];
      float4 f1 = s2f4[(size_t)(i0+1)*32 + d32];
      float4 r;
      r.x = f0.x + (f1.x - f0.x)*w; r.y = f0.y + (f1.y - f0.y)*w;
      r.z = f0.z + (f1.z - f0.z)*w; r.w = f0.w + (f1.w - f0.w)*w;
      s2L4[k*33 + d32] = r;
    }
  }
  {
    const int smi = t >> 4, q = t & 15;
    const int m = mb*16 + smi;
    float twm = tw[b*MW + m];
    float x = fminf(fmaxf(twm / T1, 0.f), 1.f) * (float)(N1-1);
    int i0 = (int)x; i0 = max(0, min(i0, N1-2));
    float w = x - (float)i0;
    #pragma unroll
    for (int j = 0; j < 2; j++) {
      int d4 = q + 16*j;
      float4 f0 = s1f4[(size_t)i0*32 + d4];
      float4 f1 = s1f4[(size_t)(i0+1)*32 + d4];
      float4 r;
      r.x = f0.x + (f1.x - f0.x)*w; r.y = f0.y + (f1.y - f0.y)*w;
      r.z = f0.z + (f1.z - f0.z)*w; r.w = f0.w + (f1.w - f0.w)*w;
      s1L4[smi*33 + d4] = r;
    }
  }
  if (t < 16) {
    int m = mb*16 + t, g = b*MW + m;
    float twm = tw[g];
    float prev = (m > 0) ? tw[g-1] : twm;
    float next = (m < MW-1) ? tw[g+1] : twm;
    wtsL[t] = 0.5f*(next - prev);
    float lbm = glb_lb[g]*T2, ubm = glb_ub[g]*T2;
    lbL[t] = lbm; ubL[t] = ubm;
    matchL[t] = (feq(lbm, lb0) && feq(ubm, ub0)) ? 1 : 0;
  }
  __syncthreads();

  // 2m x 3k tile: mp = t>>5 (8 m-pairs), kt = t&31 (32 k-triples)
  const int mp = t >> 5, kt = t & 31;
  const int mi0 = 2*mp, mi1 = mi0 + 1;
  float acc0[3], acc1[3];
  #pragma unroll
  for (int i = 0; i < 3; i++) { acc0[i] = 0.f; acc1[i] = 0.f; }

  if (matchL[mi0] && matchL[mi1]) {
    for (int d4 = 0; d4 < 32; d4++) {
      float4 s1a = s1L4[mi0*33 + d4];
      float4 s1b = s1L4[mi1*33 + d4];
      #pragma unroll
      for (int j = 0; j < 3; j++) {
        float4 s2v = s2L4[(kt + 32*j)*33 + d4];
        float dx = s1a.x - s2v.x, dy = s1a.y - s2v.y;
        float dz = s1a.z - s2v.z, dw = s1a.w - s2v.w;
        acc0[j] += dx*dx + dy*dy + dz*dz + dw*dw;
        float ex = s1b.x - s2v.x, ey = s1b.y - s2v.y;
        float ez = s1b.z - s2v.z, ew = s1b.w - s2v.w;
        acc1[j] += ex*ex + ey*ey + ez*ez + ew*ew;
      }
    }
  } else {
    // generic per-row (mirrors old per-row match decision exactly)
    #pragma unroll 1
    for (int rr = 0; rr < 2; rr++) {
      const int mi = mi0 + rr;
      float* accp = rr ? acc1 : acc0;
      if (matchL[mi]) {
        for (int d4 = 0; d4 < 32; d4++) {
          float4 s1v = s1L4[mi*33 + d4];
          #pragma unroll
          for (int j = 0; j < 3; j++) {
            float4 s2v = s2L4[(kt + 32*j)*33 + d4];
            float dx = s1v.x - s2v.x, dy = s1v.y - s2v.y;
            float dz = s1v.z - s2v.z, dw = s1v.w - s2v.w;
            accp[j] += dx*dx + dy*dy + dz*dz + dw*dw;
          }
        }
      } else {
        const float lbm = lbL[mi], ubm = ubL[mi];
        int i0a[3]; float wa[3];
        #pragma unroll
        for (int j = 0; j < 3; j++) {
          int k = kt + 32*j;
          float tau = lbm + (ubm - lbm) * (float)k * (1.0f/95.0f);
          float x = fminf(fmaxf(tau / T2, 0.f), 1.f) * (float)(N2-1);
          int i0 = (int)x; i0 = max(0, min(i0, N2-2));
          i0a[j] = i0; wa[j] = x - (float)i0;
        }
        for (int d4 = 0; d4 < 32; d4++) {
          float4 s1v = s1L4[mi*33 + d4];
          #pragma unroll
          for (int j = 0; j < 3; j++) {
            float4 f0 = s2f4[(size_t)i0a[j]*32 + d4];
            float4 f1 = s2f4[(size_t)(i0a[j]+1)*32 + d4];
            float w = wa[j];
            float ax = f0.x + (f1.x - f0.x)*w, ay = f0.y + (f1.y - f0.y)*w;
            float az = f0.z + (f1.z - f0.z)*w, aw = f0.w + (f1.w - f0.w)*w;
            float dx = s1v.x - ax, dy = s1v.y - ay, dz = s1v.z - az, dw = s1v.w - aw;
            accp[j] += dx*dx + dy*dy + dz*dz + dw*dw;
          }
        }
      }
    }
  }
  {
    #pragma unroll
    for (int rr = 0; rr < 2; rr++) {
      const int mi = mi0 + rr;
      const int m = mb*16 + mi;
      const float wts = wtsL[mi];
      const float lbm = lbL[mi], ubm = ubL[mi];
      float* accp = rr ? acc1 : acc0;
      #pragma unroll
      for (int j = 0; j < 3; j++) {
        int k = kt + 32*j;
        float nodev = accp[j] * wts;
        float tau = lbm + (ubm - lbm) * (float)k * (1.0f/95.0f);
        if (m == 0)    nodev += BARRIER * tau * tau;
        if (m == MW-1) { float dd = tau - T2; nodev += BARRIER * dd * dd; }
        ndt[mi*99 + k] = nodev;
      }
    }
  }
  __syncthreads();
  float* nodeP = ws + WS_NODE + ((size_t)b*MW + mb*16)*KD;
  for (int idx = t; idx < 16*KD; idx += 256) {
    int mi2 = idx / KD, kv = idx - mi2*KD;
    nodeP[idx] = ndt[mi2*99 + kv];
  }
}

// ---------------- KB: fused DP + readout (512 threads) ----------------
// R8: (a) ndmL row-min with per-lane rotated column start — kills the
// all-lanes-same-bank conflict (lane stride 96 words ≡ 0 mod 32);
// (b) DP prefetch packed: prmL float4 + dtL (1 b128 + 1 b32 broadcast vs 6
// scalar reads); (c) main-path 3e38 clamps removed (values bounded ~1e6;
// inf/NaN confined to discarded lanes / exp(-inf)=0 terms — bit-identical);
// (d) fallback readout float4-ized (kk-ascending sum order preserved).
__global__ __launch_bounds__(512) void k2_out(const float* __restrict__ tw,
                                              const float* __restrict__ glb_lb,
                                              const float* __restrict__ glb_ub,
                                              const float* __restrict__ reg_wt,
                                              const float* __restrict__ gubp,
                                              const float* __restrict__ t2,
                                              float* __restrict__ ws,
                                              float* __restrict__ out) {
  const int b = blockIdx.x;
  const int t = threadIdx.x;
  const int wv = t >> 6;          // 0..7
  const int lane = t & 63;
  __shared__ float ndL[MW*KD];   // 96 KB
  __shared__ float ndmL[MW];
  __shared__ float lbw[MW], ubw[MW], twv[MW];
  __shared__ float4 prmL[MW];
  __shared__ float dtL[MW];
  __shared__ float mir[2][KD];
  __shared__ float sred[32];
  __shared__ int skey[8];
  const float* __restrict__ nodeP = ws + WS_NODE + (size_t)b*MW*KD;

  // stage node -> LDS
  {
    const float4* np4 = (const float4*)nodeP;
    float4* nl4 = (float4*)ndL;
    #pragma unroll
    for (int it = 0; it < (MW*KD/4)/512; it++)
      nl4[t + 512*it] = np4[t + 512*it];
  }
  // T2 = max t2[b]
  {
    float m2 = -1e30f;
    for (int i = t; i < N2; i += 512) m2 = fmaxf(m2, t2[b*N2+i]);
    #pragma unroll
    for (int o = 32; o; o >>= 1) m2 = fmaxf(m2, __shfl_down(m2, o));
    if (lane == 0) sred[wv] = m2;
  }
  __syncthreads();
  float T2;
  {
    float v = sred[0];
    #pragma unroll
    for (int w = 1; w < 8; w++) v = fmaxf(v, sred[w]);
    T2 = v;
  }
  for (int i = t; i < MW; i += 512) {
    lbw[i] = glb_lb[b*MW+i]*T2;
    ubw[i] = glb_ub[b*MW+i]*T2;
    twv[i] = tw[b*MW+i];
  }
  const float r = reg_wt[b];
  const float gub = gubp[b];
  __syncthreads();

  // ---- rigor checks ----
  const float lb0 = lbw[0], ub0 = ubw[0];
  const float g = (ub0 - lb0) * (1.0f/95.0f);
  bool keyok = true;
  float minE1 = 3e38f, minE2 = 3e38f, maxRdt = 0.f;
  for (int i = t; i < MW; i += 512)
    keyok = keyok && (lbw[i] == lb0) && (ubw[i] == ub0);
  for (int i = t; i < MW-1; i += 512) {
    float dtv = twv[i+1] - twv[i];
    if (!(dtv > 0.f)) keyok = false;
    else {
      float rdtv = r * dtv, sl = g / dtv;
      minE1 = fminf(minE1, fminf(edgec(sl, rdtv, gub), edgec(-sl, rdtv, gub)));
      minE2 = fminf(minE2, fminf(edgec(2.f*sl, rdtv, gub), edgec(-2.f*sl, rdtv, gub)));
      maxRdt = fmaxf(maxRdt, rdtv);
    }
  }

  // ---- prefix-sum scan (waves 0-1) ----
  const bool actS = t < KD;
  const int k = actS ? t : (KD-1);
  float P = 0.f, mx = 0.f;
  if (t < 128) {
    const bool hasn = actS && (k < KD-1);
    float P2 = 0.f;
    #pragma unroll 8
    for (int m = 0; m < MW; m++) {
      float a  = ndL[m*KD + k];
      float bq = hasn ? ndL[m*KD + k + 1] : a;
      P += a; P2 += bq;
      mx = fmaxf(mx, fabsf(P - P2));
    }
    if (!actS) mx = 0.f;
  }
  {
    float wmx = mx, wE1 = minE1, wE2 = minE2, wR = maxRdt;
    #pragma unroll
    for (int o = 32; o; o >>= 1) {
      wmx = fmaxf(wmx, __shfl_xor(wmx, o));
      wE1 = fminf(wE1, __shfl_xor(wE1, o));
      wE2 = fminf(wE2, __shfl_xor(wE2, o));
      wR  = fmaxf(wR,  __shfl_xor(wR,  o));
    }
    int ka = __all(keyok ? 1 : 0);
    if (lane == 0) {
      sred[wv*4+0] = wmx; sred[wv*4+1] = wE1;
      sred[wv*4+2] = wE2; sred[wv*4+3] = wR;
      skey[wv] = ka;
    }
  }
  __syncthreads();
  float MX, E1, E2, RD; int KAll;
  {
    float a0 = sred[0], a1 = sred[1], a2 = sred[2], a3 = sred[3];
    int kk2 = skey[0];
    #pragma unroll
    for (int w = 1; w < 8; w++) {
      a0 = fmaxf(a0, sred[w*4+0]);
      a1 = fminf(a1, sred[w*4+1]);
      a2 = fminf(a2, sred[w*4+2]);
      a3 = fmaxf(a3, sred[w*4+3]);
      kk2 = kk2 && skey[w];
    }
    MX = a0; E1 = a1; E2 = a2; RD = a3; KAll = kk2;
  }
  const bool ok = KAll &&
                  (2.0f*MX   <= E1 - RD - 3.0f) &&
                  (190.0f*MX <= E2 - RD - 3.0f);

  if (ok) {
    // fast path (untouched)
    __syncthreads();
    float s = actS ? P : 3e38f;
    float mnv = s;
    #pragma unroll
    for (int o = 32; o; o >>= 1) mnv = fminf(mnv, __shfl_xor(mnv, o));
    if (lane == 0) sred[wv] = mnv;
    __syncthreads();
    float mn;
    {
      float v = sred[0];
      #pragma unroll
      for (int w = 1; w < 8; w++) v = fminf(v, sred[w]);
      mn = v;
    }
    float w = actS ? __expf((mn - P) * INVG) : 0.f;
    float num = w * (float)k, den = w;
    #pragma unroll
    for (int o = 32; o; o >>= 1) {
      num += __shfl_xor(num, o);
      den += __shfl_xor(den, o);
    }
    if (lane == 0) { sred[8+wv] = num; sred[16+wv] = den; }
    __syncthreads();
    float nsum, dsum;
    {
      float n0 = sred[8], d0 = sred[16];
      #pragma unroll
      for (int w2 = 1; w2 < 8; w2++) { n0 += sred[8+w2]; d0 += sred[16+w2]; }
      nsum = n0; dsum = d0;
    }
    const float q = (nsum / dsum) * (1.0f/95.0f);
    for (int m = t; m < MW; m += 512)
      out[b*MW + m] = lbw[m] + (ubw[m] - lbw[m]) * q;
    return;
  }

  // ---------- generic fallback ----------
  {
    // packed per-step params (bit-identical values; same dt subtraction)
    for (int i = t; i < MW-1; i += 512) {
      float4 p; p.x = lbw[i]; p.y = ubw[i]; p.z = lbw[i+1]; p.w = ubw[i+1];
      prmL[i] = p;
      dtL[i] = twv[i+1] - twv[i];
    }
    // ndmL: rotated row-min, conflict-free; fmin order-free (no NaNs)
    if (t < MW) {
      const float* rowp = &ndL[t*KD];
      float mnv = 3e38f;
      int c = lane;
      #pragma unroll 8
      for (int j = 0; j < KD; j++) {
        mnv = fminf(mnv, rowp[c]);
        c++; if (c >= KD) c -= KD;
      }
      ndmL[t] = mnv;
    }
    __syncthreads();

    if (t < 128) {
      const int dir = t >> 6;
      const bool act = lane < 48;
      const int k0i = 2*lane, k1i = 2*lane+1;
      const float frk0 = (float)k0i*(1.f/95.f), frk1 = (float)k1i*(1.f/95.f);
      float* __restrict__ outP = ws + (dir ? WS_BBUF : WS_ABUF) + (size_t)b*MW*KD;

      float a0 = 3e38f, a1 = 3e38f;
      {
        const int m0 = dir ? (MW-1) : 0;
        if (act) {
          a0 = ndL[m0*KD + k0i]; a1 = ndL[m0*KD + k1i];
          mir[dir][k0i] = a0; mir[dir][k1i] = a1;
          float2 o; o.x = dir ? 0.f : a0; o.y = dir ? 0.f : a1;
          *(float2*)&outP[(size_t)m0*KD + k0i] = o;
        }
      }
      float Blo;
      {
        float bl = act ? fminf(a0, a1) : 3e38f;
        #pragma unroll
        for (int o = 1; o < 64; o <<= 1) bl = fminf(bl, __shfl_xor(bl, o));
        Blo = bl;
      }
      float e00=3e38f,e0m=3e38f,e0p=3e38f,e10=3e38f,e1m=3e38f,e1p=3e38f;
      float eo0=3e38f, eo1=3e38f, eminmin=0.f;
      float cL1=__int_as_float(0x7fc00000), cU1=cL1, cL2=cL1, cU2=cL1, cdt=cL1;

      float4 pprm; float pdt; float pnd0=0.f, pnd1=0.f, pndm;
      {
        const int i0_ = dir ? (MW-2) : 0;
        pprm = prmL[i0_]; pdt = dtL[i0_];
        const int mn_ = dir ? i0_ : (i0_+1);
        if (act) { float2 v = *(const float2*)&ndL[mn_*KD + k0i]; pnd0=v.x; pnd1=v.y; }
        pndm = ndmL[mn_];
      }

      for (int step = 0; step < MW-1; step++) {
        const float L1=pprm.x, U1=pprm.y, L2=pprm.z, U2=pprm.w;
        const float dt = pdt;
        const float nd0=pnd0, nd1=pnd1, ndmn=pndm;
        {
          const int sn = (step+1 < MW-1) ? (step+1) : step;
          const int in_ = dir ? (MW-2-sn) : sn;
          pprm = prmL[in_]; pdt = dtL[in_];
          const int mn_ = dir ? in_ : (in_+1);
          if (act) { float2 v = *(const float2*)&ndL[mn_*KD + k0i]; pnd0=v.x; pnd1=v.y; }
          pndm = ndmL[mn_];
        }
        const bool kc = !(feq(L1,cL1)&&feq(U1,cU1)&&feq(L2,cL2)&&feq(U2,cU2)&&feq(dt,cdt));
        if (kc) {
          cL1=L1; cU1=U1; cL2=L2; cU2=U2; cdt=dt;
          float bl = act ? fminf(mir[dir][k0i], mir[dir][k1i]) : 3e38f;
          #pragma unroll
          for (int o = 1; o < 64; o <<= 1) bl = fminf(bl, __shfl_xor(bl, o));
          Blo = bl;
          const float invdt = 1.f/dt, rdt = r*dt;
          const float my0 = dir ? (L1+(U1-L1)*frk0) : (L2+(U2-L2)*frk0);
          const float my1 = dir ? (L1+(U1-L1)*frk1) : (L2+(U2-L2)*frk1);
          e00=3e38f; e0m=3e38f; e0p=3e38f; e10=3e38f; e1m=3e38f; e1p=3e38f;
          eo0=3e38f; eo1=3e38f;
          float emn = 3e38f;
          for (int j = 0; j < KD; j++) {
            const float frj = (float)j*(1.f/95.f);
            const float oth = dir ? (L2+(U2-L2)*frj) : (L1+(U1-L1)*frj);
            const float sl0 = (dir ? (oth-my0) : (my0-oth))*invdt;
            const float sl1 = (dir ? (oth-my1) : (my1-oth))*invdt;
            float d0=sl0-1.f, g0=fminf(sl0,0.f), v0=fmaxf(sl0-gub,0.f);
            float ej0 = rdt*d0*d0 + BARRIER*(g0*g0+v0*v0);
            float d1=sl1-1.f, g1=fminf(sl1,0.f), v1=fmaxf(sl1-gub,0.f);
            float ej1 = rdt*d1*d1 + BARRIER*(g1*g1+v1*v1);
            emn = fminf(emn, fminf(ej0, ej1));
            if      (j == k0i-1) e0m = ej0;
            else if (j == k0i)   e00 = ej0;
            else if (j == k0i+1) e0p = ej0;
            else                 eo0 = fminf(eo0, ej0);
            if      (j == k1i-1) e1m = ej1;
            else if (j == k1i)   e10 = ej1;
            else if (j == k1i+1) e1p = ej1;
            else                 eo1 = fminf(eo1, ej1);
          }
          if (!act) emn = 3e38f;
          #pragma unroll
          for (int o = 1; o < 64; o <<= 1) emn = fminf(emn, __shfl_xor(emn, o));
          eminmin = emn;
        }
        const float a1p = dpp_shr1(a1);
        const float a0n = dpp_shl1(a0);
        // clamps removed: act-lane values bounded ~1e6; inf/NaN cases land in
        // discarded lanes or exp(-inf)=0 terms — bit-identical to clamped.
        const float x0m = a1p + e0m;
        const float x00 = a0  + e00;
        const float x0p = a1  + e0p;
        const float x1m = a0  + e1m;
        const float x10 = a1  + e10;
        const float x1p = a0n + e1p;
        float mn0 = fminf(fminf(x0m, x00), x0p);
        float mn1 = fminf(fminf(x1m, x10), x1p);
        float sum0 = __expf((mn0-x0m)*INVG) + __expf((mn0-x00)*INVG) + __expf((mn0-x0p)*INVG);
        float sum1 = __expf((mn1-x1m)*INVG) + __expf((mn1-x10)*INVG) + __expf((mn1-x1p)*INVG);
        const bool bad = act && ((Blo + eo0 - mn0 < 8.7f) || (Blo + eo1 - mn1 < 8.7f));
        if (__any((int)bad)) {
          const float invdt = 1.f/dt, rdt = r*dt;
          const float my0 = dir ? (L1+(U1-L1)*frk0) : (L2+(U2-L2)*frk0);
          const float my1 = dir ? (L1+(U1-L1)*frk1) : (L2+(U2-L2)*frk1);
          mn0 = 3e38f; mn1 = 3e38f;
          for (int j = 0; j < KD; j++) {
            const float sj = mir[dir][j];
            const float frj = (float)j*(1.f/95.f);
            const float oth = dir ? (L2+(U2-L2)*frj) : (L1+(U1-L1)*frj);
            const float sl0 = (dir ? (oth-my0) : (my0-oth))*invdt;
            const float sl1 = (dir ? (oth-my1) : (my1-oth))*invdt;
            float d0=sl0-1.f, g0=fminf(sl0,0.f), v0=fmaxf(sl0-gub,0.f);
            float ej0 = rdt*d0*d0 + BARRIER*(g0*g0+v0*v0);
            float d1=sl1-1.f, g1=fminf(sl1,0.f), v1=fmaxf(sl1-gub,0.f);
            float ej1 = rdt*d1*d1 + BARRIER*(g1*g1+v1*v1);
            mn0 = fminf(mn0, fminf(sj + ej0, 3e38f));
            mn1 = fminf(mn1, fminf(sj + ej1, 3e38f));
          }
          sum0 = 0.f; sum1 = 0.f;
          for (int j = 0; j < KD; j++) {
            const float sj = mir[dir][j];
            const float frj = (float)j*(1.f/95.f);
            const float oth = dir ? (L2+(U2-L2)*frj) : (L1+(U1-L1)*frj);
            const float sl0 = (dir ? (oth-my0) : (my0-oth))*invdt;
            const float sl1 = (dir ? (oth-my1) : (my1-oth))*invdt;
            float d0=sl0-1.f, g0=fminf(sl0,0.f), v0=fmaxf(sl0-gub,0.f);
            float ej0 = rdt*d0*d0 + BARRIER*(g0*g0+v0*v0);
            float d1=sl1-1.f, g1=fminf(sl1,0.f), v1=fmaxf(sl1-gub,0.f);
            float ej1 = rdt*d1*d1 + BARRIER*(g1*g1+v1*v1);
            sum0 += __expf((mn0 - fminf(sj + ej0, 3e38f))*INVG);
            sum1 += __expf((mn1 - fminf(sj + ej1, 3e38f))*INVG);
          }
        }
        const float sv0 = mn0 - GAM*__logf(sum0);
        const float sv1 = mn1 - GAM*__logf(sum1);
        const float na0 = nd0 + sv0, na1 = nd1 + sv1;
        const int ic = dir ? (MW-2-step) : step;
        const int mnode = dir ? ic : (ic+1);
        if (act) {
          mir[dir][k0i] = na0; mir[dir][k1i] = na1;
          float2 o; o.x = dir ? sv0 : na0; o.y = dir ? sv1 : na1;
          *(float2*)&outP[(size_t)mnode*KD + k0i] = o;
        }
        a0 = act ? na0 : 3e38f;
        a1 = act ? na1 : 3e38f;
        Blo += eminmin + ndmn - 0.4575f;
      }
    }

    // in-block readout (fallback only; float4 loads, kk-order preserved)
    __threadfence_block();
    __syncthreads();
    const float* __restrict__ Ab = ws + WS_ABUF + (size_t)b*MW*KD;
    const float* __restrict__ Bb = ws + WS_BBUF + (size_t)b*MW*KD;
    for (int m = t; m < MW; m += 512) {
      const float4* Ab4 = (const float4*)&Ab[(size_t)m*KD];
      const float4* Bb4 = (const float4*)&Bb[(size_t)m*KD];
      float mnv = 3e38f;
      #pragma unroll 4
      for (int q = 0; q < KD/4; q++) {
        float4 av = Ab4[q], bv = Bb4[q];
        mnv = fminf(mnv, fminf(fminf(av.x+bv.x, av.y+bv.y),
                               fminf(av.z+bv.z, av.w+bv.w)));
      }
      float num = 0.f, den = 0.f;
      #pragma unroll 4
      for (int q = 0; q < KD/4; q++) {
        float4 av = Ab4[q], bv = Bb4[q];
        float w0 = __expf((mnv - (av.x+bv.x)) * INVG);
        float w1 = __expf((mnv - (av.y+bv.y)) * INVG);
        float w2 = __expf((mnv - (av.z+bv.z)) * INVG);
        float w3 = __expf((mnv - (av.w+bv.w)) * INVG);
        num += w0 * (float)(4*q+0); den += w0;
        num += w1 * (float)(4*q+1); den += w1;
        num += w2 * (float)(4*q+2); den += w2;
        num += w3 * (float)(4*q+3); den += w3;
      }
      out[b*MW + m] = lbw[m] + (ubw[m] - lbw[m]) * (num/den) * (1.0f/95.0f);
    }
  }
}

extern "C" void kernel_launch(void* const* d_in, const int* in_sizes, int n_in,
                              void* d_out, int out_size, void* d_ws, size_t ws_size,
                              hipStream_t stream) {
  const float* s1f    = (const float*)d_in[0];
  const float* s2f    = (const float*)d_in[1];
  const float* regw   = (const float*)d_in[2];
  const float* glb_lb = (const float*)d_in[3];
  const float* glb_ub = (const float*)d_in[4];
  const float* gubp   = (const float*)d_in[5];
  const float* t1     = (const float*)d_in[6];
  const float* t2     = (const float*)d_in[7];
  const float* twp    = (const float*)d_in[8];
  float* ws  = (float*)d_ws;
  float* out = (float*)d_out;

  dim3 g1(16, NB);
  k1_node<<<g1, 256, 0, stream>>>(s1f, s2f, twp, glb_lb, glb_ub, t1, t2, ws);
  k2_out<<<NB, 512, 0, stream>>>(twp, glb_lb, glb_ub, regw, gubp, t2, ws, out);
}

// Round 9
// 104.699 us; speedup vs baseline: 1.2460x; 1.0169x over previous
//
#include <hip/hip_runtime.h>

#define NB 32
#define N1 512
#define N2 512
#define DF 128
#define MW 256
#define KD 96
#define INVG 10.0f
#define GAM 0.1f
#define BARRIER 10000.0f

// ws layout (floats)
#define WS_NODE  0
#define WS_ABUF  (WS_NODE + NB*MW*KD)
#define WS_BBUF  (WS_ABUF + NB*MW*KD)

__device__ __forceinline__ bool feq(float a, float b) {
  return fabsf(a - b) <= 1e-4f * fmaxf(fabsf(a), fabsf(b)) + 1e-12f;
}

__device__ __forceinline__ float edgec(float s, float rdtv, float gub) {
  float d = s - 1.0f, ng = fminf(s, 0.f), ov = fmaxf(s - gub, 0.f);
  return rdtv*d*d + BARRIER*(ng*ng + ov*ov);
}

// 1-lane whole-wave shifts via DPP (neutral vs shfl per R7; kept).
__device__ __forceinline__ float dpp_shr1(float x) {
  return __int_as_float(__builtin_amdgcn_update_dpp(
      0, __float_as_int(x), 0x138, 0xf, 0xf, true));
}
__device__ __forceinline__ float dpp_shl1(float x) {
  return __int_as_float(__builtin_amdgcn_update_dpp(
      0, __float_as_int(x), 0x130, 0xf, 0xf, true));
}

// ---------------- KA: fused rowmax + node costs ----------------
// R9: XCD-aware remap — 1D grid of 512; all 16 producers of batch b land on
// XCD b%8 (round-robin blockIdx->XCD heuristic), matching k2 block b's XCD.
// Node matrix lines then stay dirty in the CONSUMER's local L2 instead of
// scattered across 8 remote L2s (R8 ledger: k2 staging ~16 us = remote-dirty
// read signature). Pure placement change — every block computes identical
// values -> output bit-identical.
__global__ __launch_bounds__(256) void k1_node(const float* __restrict__ s1f,
                                               const float* __restrict__ s2f,
                                               const float* __restrict__ tw,
                                               const float* __restrict__ glb_lb,
                                               const float* __restrict__ glb_ub,
                                               const float* __restrict__ t1,
                                               const float* __restrict__ t2,
                                               float* __restrict__ ws) {
  const int id   = blockIdx.x;        // 0..511
  const int xcd  = id & 7;
  const int slot = id >> 3;           // 0..63
  const int b    = xcd + 8*(slot >> 4);  // batch: b % 8 == xcd
  const int mb   = slot & 15;         // m-tile 0..15
  const int t  = threadIdx.x;
  const int lane = t & 63;
  const int wv = t >> 6;
  __shared__ float s1L[16*132];
  __shared__ float s2L[96*132];
  __shared__ float ndt[16*99];
  __shared__ float wtsL[16], lbL[16], ubL[16];
  __shared__ int   matchL[16];
  __shared__ float redm[8];

  {
    float m1 = -1e30f, m2 = -1e30f;
    for (int i = t; i < N1; i += 256) m1 = fmaxf(m1, t1[b*N1+i]);
    for (int i = t; i < N2; i += 256) m2 = fmaxf(m2, t2[b*N2+i]);
    #pragma unroll
    for (int o = 32; o; o >>= 1) {
      m1 = fmaxf(m1, __shfl_down(m1, o));
      m2 = fmaxf(m2, __shfl_down(m2, o));
    }
    if (lane == 0) { redm[wv] = m1; redm[4+wv] = m2; }
  }
  __syncthreads();
  const float T1 = fmaxf(fmaxf(redm[0], redm[1]), fmaxf(redm[2], redm[3]));
  const float T2 = fmaxf(fmaxf(redm[4], redm[5]), fmaxf(redm[6], redm[7]));
  const float lb0 = glb_lb[b*MW] * T2;
  const float ub0 = glb_ub[b*MW] * T2;
  float4* s1L4 = (float4*)s1L;
  float4* s2L4 = (float4*)s2L;
  const float4* s1f4 = (const float4*)(s1f + (size_t)b*N1*DF);
  const float4* s2f4 = (const float4*)(s2f + (size_t)b*N2*DF);

  {
    const int d32 = t & 31;
    const int k8  = t >> 5;
    #pragma unroll
    for (int kk = 0; kk < 12; kk++) {
      int k = k8 + 8*kk;
      float tau = lb0 + (ub0 - lb0) * (float)k * (1.0f/95.0f);
      float x = fminf(fmaxf(tau / T2, 0.f), 1.f) * (float)(N2-1);
      int i0 = (int)x; i0 = max(0, min(i0, N2-2));
      float w = x - (float)i0;
      float4 f0 = s2f4[(size_t)i0*32 + d32];
      float4 f1 = s2f4[(size_t)(i0+1)*32 + d32];
      float4 r;
      r.x = f0.x + (f1.x - f0.x)*w; r.y = f0.y + (f1.y - f0.y)*w;
      r.z = f0.z + (f1.z - f0.z)*w; r.w = f0.w + (f1.w - f0.w)*w;
      s2L4[k*33 + d32] = r;
    }
  }
  {
    const int smi = t >> 4, q = t & 15;
    const int m = mb*16 + smi;
    float twm = tw[b*MW + m];
    float x = fminf(fmaxf(twm / T1, 0.f), 1.f) * (float)(N1-1);
    int i0 = (int)x; i0 = max(0, min(i0, N1-2));
    float w = x - (float)i0;
    #pragma unroll
    for (int j = 0; j < 2; j++) {
      int d4 = q + 16*j;
      float4 f0 = s1f4[(size_t)i0*32 + d4];
      float4 f1 = s1f4[(size_t)(i0+1)*32 + d4];
      float4 r;
      r.x = f0.x + (f1.x - f0.x)*w; r.y = f0.y + (f1.y - f0.y)*w;
      r.z = f0.z + (f1.z - f0.z)*w; r.w = f0.w + (f1.w - f0.w)*w;
      s1L4[smi*33 + d4] = r;
    }
  }
  if (t < 16) {
    int m = mb*16 + t, g = b*MW + m;
    float twm = tw[g];
    float prev = (m > 0) ? tw[g-1] : twm;
    float next = (m < MW-1) ? tw[g+1] : twm;
    wtsL[t] = 0.5f*(next - prev);
    float lbm = glb_lb[g]*T2, ubm = glb_ub[g]*T2;
    lbL[t] = lbm; ubL[t] = ubm;
    matchL[t] = (feq(lbm, lb0) && feq(ubm, ub0)) ? 1 : 0;
  }
  __syncthreads();

  // 2m x 3k tile: mp = t>>5 (8 m-pairs), kt = t&31 (32 k-triples)
  const int mp = t >> 5, kt = t & 31;
  const int mi0 = 2*mp, mi1 = mi0 + 1;
  float acc0[3], acc1[3];
  #pragma unroll
  for (int i = 0; i < 3; i++) { acc0[i] = 0.f; acc1[i] = 0.f; }

  if (matchL[mi0] && matchL[mi1]) {
    for (int d4 = 0; d4 < 32; d4++) {
      float4 s1a = s1L4[mi0*33 + d4];
      float4 s1b = s1L4[mi1*33 + d4];
      #pragma unroll
      for (int j = 0; j < 3; j++) {
        float4 s2v = s2L4[(kt + 32*j)*33 + d4];
        float dx = s1a.x - s2v.x, dy = s1a.y - s2v.y;
        float dz = s1a.z - s2v.z, dw = s1a.w - s2v.w;
        acc0[j] += dx*dx + dy*dy + dz*dz + dw*dw;
        float ex = s1b.x - s2v.x, ey = s1b.y - s2v.y;
        float ez = s1b.z - s2v.z, ew = s1b.w - s2v.w;
        acc1[j] += ex*ex + ey*ey + ez*ez + ew*ew;
      }
    }
  } else {
    #pragma unroll 1
    for (int rr = 0; rr < 2; rr++) {
      const int mi = mi0 + rr;
      float* accp = rr ? acc1 : acc0;
      if (matchL[mi]) {
        for (int d4 = 0; d4 < 32; d4++) {
          float4 s1v = s1L4[mi*33 + d4];
          #pragma unroll
          for (int j = 0; j < 3; j++) {
            float4 s2v = s2L4[(kt + 32*j)*33 + d4];
            float dx = s1v.x - s2v.x, dy = s1v.y - s2v.y;
            float dz = s1v.z - s2v.z, dw = s1v.w - s2v.w;
            accp[j] += dx*dx + dy*dy + dz*dz + dw*dw;
          }
        }
      } else {
        const float lbm = lbL[mi], ubm = ubL[mi];
        int i0a[3]; float wa[3];
        #pragma unroll
        for (int j = 0; j < 3; j++) {
          int k = kt + 32*j;
          float tau = lbm + (ubm - lbm) * (float)k * (1.0f/95.0f);
          float x = fminf(fmaxf(tau / T2, 0.f), 1.f) * (float)(N2-1);
          int i0 = (int)x; i0 = max(0, min(i0, N2-2));
          i0a[j] = i0; wa[j] = x - (float)i0;
        }
        for (int d4 = 0; d4 < 32; d4++) {
          float4 s1v = s1L4[mi*33 + d4];
          #pragma unroll
          for (int j = 0; j < 3; j++) {
            float4 f0 = s2f4[(size_t)i0a[j]*32 + d4];
            float4 f1 = s2f4[(size_t)(i0a[j]+1)*32 + d4];
            float w = wa[j];
            float ax = f0.x + (f1.x - f0.x)*w, ay = f0.y + (f1.y - f0.y)*w;
            float az = f0.z + (f1.z - f0.z)*w, aw = f0.w + (f1.w - f0.w)*w;
            float dx = s1v.x - ax, dy = s1v.y - ay, dz = s1v.z - az, dw = s1v.w - aw;
            accp[j] += dx*dx + dy*dy + dz*dz + dw*dw;
          }
        }
      }
    }
  }
  {
    #pragma unroll
    for (int rr = 0; rr < 2; rr++) {
      const int mi = mi0 + rr;
      const int m = mb*16 + mi;
      const float wts = wtsL[mi];
      const float lbm = lbL[mi], ubm = ubL[mi];
      float* accp = rr ? acc1 : acc0;
      #pragma unroll
      for (int j = 0; j < 3; j++) {
        int k = kt + 32*j;
        float nodev = accp[j] * wts;
        float tau = lbm + (ubm - lbm) * (float)k * (1.0f/95.0f);
        if (m == 0)    nodev += BARRIER * tau * tau;
        if (m == MW-1) { float dd = tau - T2; nodev += BARRIER * dd * dd; }
        ndt[mi*99 + k] = nodev;
      }
    }
  }
  __syncthreads();
  float* nodeP = ws + WS_NODE + ((size_t)b*MW + mb*16)*KD;
  for (int idx = t; idx < 16*KD; idx += 256) {
    int mi2 = idx / KD, kv = idx - mi2*KD;
    nodeP[idx] = ndt[mi2*99 + kv];
  }
}

// ---------------- KB: fused DP + readout (512 threads; UNCHANGED from R8) ----------------
__global__ __launch_bounds__(512) void k2_out(const float* __restrict__ tw,
                                              const float* __restrict__ glb_lb,
                                              const float* __restrict__ glb_ub,
                                              const float* __restrict__ reg_wt,
                                              const float* __restrict__ gubp,
                                              const float* __restrict__ t2,
                                              float* __restrict__ ws,
                                              float* __restrict__ out) {
  const int b = blockIdx.x;
  const int t = threadIdx.x;
  const int wv = t >> 6;          // 0..7
  const int lane = t & 63;
  __shared__ float ndL[MW*KD];   // 96 KB
  __shared__ float ndmL[MW];
  __shared__ float lbw[MW], ubw[MW], twv[MW];
  __shared__ float4 prmL[MW];
  __shared__ float dtL[MW];
  __shared__ float mir[2][KD];
  __shared__ float sred[32];
  __shared__ int skey[8];
  const float* __restrict__ nodeP = ws + WS_NODE + (size_t)b*MW*KD;

  // stage node -> LDS
  {
    const float4* np4 = (const float4*)nodeP;
    float4* nl4 = (float4*)ndL;
    #pragma unroll
    for (int it = 0; it < (MW*KD/4)/512; it++)
      nl4[t + 512*it] = np4[t + 512*it];
  }
  // T2 = max t2[b]
  {
    float m2 = -1e30f;
    for (int i = t; i < N2; i += 512) m2 = fmaxf(m2, t2[b*N2+i]);
    #pragma unroll
    for (int o = 32; o; o >>= 1) m2 = fmaxf(m2, __shfl_down(m2, o));
    if (lane == 0) sred[wv] = m2;
  }
  __syncthreads();
  float T2;
  {
    float v = sred[0];
    #pragma unroll
    for (int w = 1; w < 8; w++) v = fmaxf(v, sred[w]);
    T2 = v;
  }
  for (int i = t; i < MW; i += 512) {
    lbw[i] = glb_lb[b*MW+i]*T2;
    ubw[i] = glb_ub[b*MW+i]*T2;
    twv[i] = tw[b*MW+i];
  }
  const float r = reg_wt[b];
  const float gub = gubp[b];
  __syncthreads();

  // ---- rigor checks ----
  const float lb0 = lbw[0], ub0 = ubw[0];
  const float g = (ub0 - lb0) * (1.0f/95.0f);
  bool keyok = true;
  float minE1 = 3e38f, minE2 = 3e38f, maxRdt = 0.f;
  for (int i = t; i < MW; i += 512)
    keyok = keyok && (lbw[i] == lb0) && (ubw[i] == ub0);
  for (int i = t; i < MW-1; i += 512) {
    float dtv = twv[i+1] - twv[i];
    if (!(dtv > 0.f)) keyok = false;
    else {
      float rdtv = r * dtv, sl = g / dtv;
      minE1 = fminf(minE1, fminf(edgec(sl, rdtv, gub), edgec(-sl, rdtv, gub)));
      minE2 = fminf(minE2, fminf(edgec(2.f*sl, rdtv, gub), edgec(-2.f*sl, rdtv, gub)));
      maxRdt = fmaxf(maxRdt, rdtv);
    }
  }

  // ---- prefix-sum scan (waves 0-1) ----
  const bool actS = t < KD;
  const int k = actS ? t : (KD-1);
  float P = 0.f, mx = 0.f;
  if (t < 128) {
    const bool hasn = actS && (k < KD-1);
    float P2 = 0.f;
    #pragma unroll 8
    for (int m = 0; m < MW; m++) {
      float a  = ndL[m*KD + k];
      float bq = hasn ? ndL[m*KD + k + 1] : a;
      P += a; P2 += bq;
      mx = fmaxf(mx, fabsf(P - P2));
    }
    if (!actS) mx = 0.f;
  }
  {
    float wmx = mx, wE1 = minE1, wE2 = minE2, wR = maxRdt;
    #pragma unroll
    for (int o = 32; o; o >>= 1) {
      wmx = fmaxf(wmx, __shfl_xor(wmx, o));
      wE1 = fminf(wE1, __shfl_xor(wE1, o));
      wE2 = fminf(wE2, __shfl_xor(wE2, o));
      wR  = fmaxf(wR,  __shfl_xor(wR,  o));
    }
    int ka = __all(keyok ? 1 : 0);
    if (lane == 0) {
      sred[wv*4+0] = wmx; sred[wv*4+1] = wE1;
      sred[wv*4+2] = wE2; sred[wv*4+3] = wR;
      skey[wv] = ka;
    }
  }
  __syncthreads();
  float MX, E1, E2, RD; int KAll;
  {
    float a0 = sred[0], a1 = sred[1], a2 = sred[2], a3 = sred[3];
    int kk2 = skey[0];
    #pragma unroll
    for (int w = 1; w < 8; w++) {
      a0 = fmaxf(a0, sred[w*4+0]);
      a1 = fminf(a1, sred[w*4+1]);
      a2 = fminf(a2, sred[w*4+2]);
      a3 = fmaxf(a3, sred[w*4+3]);
      kk2 = kk2 && skey[w];
    }
    MX = a0; E1 = a1; E2 = a2; RD = a3; KAll = kk2;
  }
  const bool ok = KAll &&
                  (2.0f*MX   <= E1 - RD - 3.0f) &&
                  (190.0f*MX <= E2 - RD - 3.0f);

  if (ok) {
    // fast path
    __syncthreads();
    float s = actS ? P : 3e38f;
    float mnv = s;
    #pragma unroll
    for (int o = 32; o; o >>= 1) mnv = fminf(mnv, __shfl_xor(mnv, o));
    if (lane == 0) sred[wv] = mnv;
    __syncthreads();
    float mn;
    {
      float v = sred[0];
      #pragma unroll
      for (int w = 1; w < 8; w++) v = fminf(v, sred[w]);
      mn = v;
    }
    float w = actS ? __expf((mn - P) * INVG) : 0.f;
    float num = w * (float)k, den = w;
    #pragma unroll
    for (int o = 32; o; o >>= 1) {
      num += __shfl_xor(num, o);
      den += __shfl_xor(den, o);
    }
    if (lane == 0) { sred[8+wv] = num; sred[16+wv] = den; }
    __syncthreads();
    float nsum, dsum;
    {
      float n0 = sred[8], d0 = sred[16];
      #pragma unroll
      for (int w2 = 1; w2 < 8; w2++) { n0 += sred[8+w2]; d0 += sred[16+w2]; }
      nsum = n0; dsum = d0;
    }
    const float q = (nsum / dsum) * (1.0f/95.0f);
    for (int m = t; m < MW; m += 512)
      out[b*MW + m] = lbw[m] + (ubw[m] - lbw[m]) * q;
    return;
  }

  // ---------- generic fallback ----------
  {
    for (int i = t; i < MW-1; i += 512) {
      float4 p; p.x = lbw[i]; p.y = ubw[i]; p.z = lbw[i+1]; p.w = ubw[i+1];
      prmL[i] = p;
      dtL[i] = twv[i+1] - twv[i];
    }
    if (t < MW) {
      const float* rowp = &ndL[t*KD];
      float mnv = 3e38f;
      int c = lane;
      #pragma unroll 8
      for (int j = 0; j < KD; j++) {
        mnv = fminf(mnv, rowp[c]);
        c++; if (c >= KD) c -= KD;
      }
      ndmL[t] = mnv;
    }
    __syncthreads();

    if (t < 128) {
      const int dir = t >> 6;
      const bool act = lane < 48;
      const int k0i = 2*lane, k1i = 2*lane+1;
      const float frk0 = (float)k0i*(1.f/95.f), frk1 = (float)k1i*(1.f/95.f);
      float* __restrict__ outP = ws + (dir ? WS_BBUF : WS_ABUF) + (size_t)b*MW*KD;

      float a0 = 3e38f, a1 = 3e38f;
      {
        const int m0 = dir ? (MW-1) : 0;
        if (act) {
          a0 = ndL[m0*KD + k0i]; a1 = ndL[m0*KD + k1i];
          mir[dir][k0i] = a0; mir[dir][k1i] = a1;
          float2 o; o.x = dir ? 0.f : a0; o.y = dir ? 0.f : a1;
          *(float2*)&outP[(size_t)m0*KD + k0i] = o;
        }
      }
      float Blo;
      {
        float bl = act ? fminf(a0, a1) : 3e38f;
        #pragma unroll
        for (int o = 1; o < 64; o <<= 1) bl = fminf(bl, __shfl_xor(bl, o));
        Blo = bl;
      }
      float e00=3e38f,e0m=3e38f,e0p=3e38f,e10=3e38f,e1m=3e38f,e1p=3e38f;
      float eo0=3e38f, eo1=3e38f, eminmin=0.f;
      float cL1=__int_as_float(0x7fc00000), cU1=cL1, cL2=cL1, cU2=cL1, cdt=cL1;

      float4 pprm; float pdt; float pnd0=0.f, pnd1=0.f, pndm;
      {
        const int i0_ = dir ? (MW-2) : 0;
        pprm = prmL[i0_]; pdt = dtL[i0_];
        const int mn_ = dir ? i0_ : (i0_+1);
        if (act) { float2 v = *(const float2*)&ndL[mn_*KD + k0i]; pnd0=v.x; pnd1=v.y; }
        pndm = ndmL[mn_];
      }

      for (int step = 0; step < MW-1; step++) {
        const float L1=pprm.x, U1=pprm.y, L2=pprm.z, U2=pprm.w;
        const float dt = pdt;
        const float nd0=pnd0, nd1=pnd1, ndmn=pndm;
        {
          const int sn = (step+1 < MW-1) ? (step+1) : step;
          const int in_ = dir ? (MW-2-sn) : sn;
          pprm = prmL[in_]; pdt = dtL[in_];
          const int mn_ = dir ? in_ : (in_+1);
          if (act) { float2 v = *(const float2*)&ndL[mn_*KD + k0i]; pnd0=v.x; pnd1=v.y; }
          pndm = ndmL[mn_];
        }
        const bool kc = !(feq(L1,cL1)&&feq(U1,cU1)&&feq(L2,cL2)&&feq(U2,cU2)&&feq(dt,cdt));
        if (kc) {
          cL1=L1; cU1=U1; cL2=L2; cU2=U2; cdt=dt;
          float bl = act ? fminf(mir[dir][k0i], mir[dir][k1i]) : 3e38f;
          #pragma unroll
          for (int o = 1; o < 64; o <<= 1) bl = fminf(bl, __shfl_xor(bl, o));
          Blo = bl;
          const float invdt = 1.f/dt, rdt = r*dt;
          const float my0 = dir ? (L1+(U1-L1)*frk0) : (L2+(U2-L2)*frk0);
          const float my1 = dir ? (L1+(U1-L1)*frk1) : (L2+(U2-L2)*frk1);
          e00=3e38f; e0m=3e38f; e0p=3e38f; e10=3e38f; e1m=3e38f; e1p=3e38f;
          eo0=3e38f; eo1=3e38f;
          float emn = 3e38f;
          for (int j = 0; j < KD; j++) {
            const float frj = (float)j*(1.f/95.f);
            const float oth = dir ? (L2+(U2-L2)*frj) : (L1+(U1-L1)*frj);
            const float sl0 = (dir ? (oth-my0) : (my0-oth))*invdt;
            const float sl1 = (dir ? (oth-my1) : (my1-oth))*invdt;
            float d0=sl0-1.f, g0=fminf(sl0,0.f), v0=fmaxf(sl0-gub,0.f);
            float ej0 = rdt*d0*d0 + BARRIER*(g0*g0+v0*v0);
            float d1=sl1-1.f, g1=fminf(sl1,0.f), v1=fmaxf(sl1-gub,0.f);
            float ej1 = rdt*d1*d1 + BARRIER*(g1*g1+v1*v1);
            emn = fminf(emn, fminf(ej0, ej1));
            if      (j == k0i-1) e0m = ej0;
            else if (j == k0i)   e00 = ej0;
            else if (j == k0i+1) e0p = ej0;
            else                 eo0 = fminf(eo0, ej0);
            if      (j == k1i-1) e1m = ej1;
            else if (j == k1i)   e10 = ej1;
            else if (j == k1i+1) e1p = ej1;
            else                 eo1 = fminf(eo1, ej1);
          }
          if (!act) emn = 3e38f;
          #pragma unroll
          for (int o = 1; o < 64; o <<= 1) emn = fminf(emn, __shfl_xor(emn, o));
          eminmin = emn;
        }
        const float a1p = dpp_shr1(a1);
        const float a0n = dpp_shl1(a0);
        const float x0m = a1p + e0m;
        const float x00 = a0  + e00;
        const float x0p = a1  + e0p;
        const float x1m = a0  + e1m;
        const float x10 = a1  + e10;
        const float x1p = a0n + e1p;
        float mn0 = fminf(fminf(x0m, x00), x0p);
        float mn1 = fminf(fminf(x1m, x10), x1p);
        float sum0 = __expf((mn0-x0m)*INVG) + __expf((mn0-x00)*INVG) + __expf((mn0-x0p)*INVG);
        float sum1 = __expf((mn1-x1m)*INVG) + __expf((mn1-x10)*INVG) + __expf((mn1-x1p)*INVG);
        const bool bad = act && ((Blo + eo0 - mn0 < 8.7f) || (Blo + eo1 - mn1 < 8.7f));
        if (__any((int)bad)) {
          const float invdt = 1.f/dt, rdt = r*dt;
          const float my0 = dir ? (L1+(U1-L1)*frk0) : (L2+(U2-L2)*frk0);
          const float my1 = dir ? (L1+(U1-L1)*frk1) : (L2+(U2-L2)*frk1);
          mn0 = 3e38f; mn1 = 3e38f;
          for (int j = 0; j < KD; j++) {
            const float sj = mir[dir][j];
            const float frj = (float)j*(1.f/95.f);
            const float oth = dir ? (L2+(U2-L2)*frj) : (L1+(U1-L1)*frj);
            const float sl0 = (dir ? (oth-my0) : (my0-oth))*invdt;
            const float sl1 = (dir ? (oth-my1) : (my1-oth))*invdt;
            float d0=sl0-1.f, g0=fminf(sl0,0.f), v0=fmaxf(sl0-gub,0.f);
            float ej0 = rdt*d0*d0 + BARRIER*(g0*g0+v0*v0);
            float d1=sl1-1.f, g1=fminf(sl1,0.f), v1=fmaxf(sl1-gub,0.f);
            float ej1 = rdt*d1*d1 + BARRIER*(g1*g1+v1*v1);
            mn0 = fminf(mn0, fminf(sj + ej0, 3e38f));
            mn1 = fminf(mn1, fminf(sj + ej1, 3e38f));
          }
          sum0 = 0.f; sum1 = 0.f;
          for (int j = 0; j < KD; j++) {
            const float sj = mir[dir][j];
            const float frj = (float)j*(1.f/95.f);
            const float oth = dir ? (L2+(U2-L2)*frj) : (L1+(U1-L1)*frj);
            const float sl0 = (dir ? (oth-my0) : (my0-oth))*invdt;
            const float sl1 = (dir ? (oth-my1) : (my1-oth))*invdt;
            float d0=sl0-1.f, g0=fminf(sl0,0.f), v0=fmaxf(sl0-gub,0.f);
            float ej0 = rdt*d0*d0 + BARRIER*(g0*g0+v0*v0);
            float d1=sl1-1.f, g1=fminf(sl1,0.f), v1=fmaxf(sl1-gub,0.f);
            float ej1 = rdt*d1*d1 + BARRIER*(g1*g1+v1*v1);
            sum0 += __expf((mn0 - fminf(sj + ej0, 3e38f))*INVG);
            sum1 += __expf((mn1 - fminf(sj + ej1, 3e38f))*INVG);
          }
        }
        const float sv0 = mn0 - GAM*__logf(sum0);
        const float sv1 = mn1 - GAM*__logf(sum1);
        const float na0 = nd0 + sv0, na1 = nd1 + sv1;
        const int ic = dir ? (MW-2-step) : step;
        const int mnode = dir ? ic : (ic+1);
        if (act) {
          mir[dir][k0i] = na0; mir[dir][k1i] = na1;
          float2 o; o.x = dir ? sv0 : na0; o.y = dir ? sv1 : na1;
          *(float2*)&outP[(size_t)mnode*KD + k0i] = o;
        }
        a0 = act ? na0 : 3e38f;
        a1 = act ? na1 : 3e38f;
        Blo += eminmin + ndmn - 0.4575f;
      }
    }

    // in-block readout (fallback only; float4 loads, kk-order preserved)
    __threadfence_block();
    __syncthreads();
    const float* __restrict__ Ab = ws + WS_ABUF + (size_t)b*MW*KD;
    const float* __restrict__ Bb = ws + WS_BBUF + (size_t)b*MW*KD;
    for (int m = t; m < MW; m += 512) {
      const float4* Ab4 = (const float4*)&Ab[(size_t)m*KD];
      const float4* Bb4 = (const float4*)&Bb[(size_t)m*KD];
      float mnv = 3e38f;
      #pragma unroll 4
      for (int q = 0; q < KD/4; q++) {
        float4 av = Ab4[q], bv = Bb4[q];
        mnv = fminf(mnv, fminf(fminf(av.x+bv.x, av.y+bv.y),
                               fminf(av.z+bv.z, av.w+bv.w)));
      }
      float num = 0.f, den = 0.f;
      #pragma unroll 4
      for (int q = 0; q < KD/4; q++) {
        float4 av = Ab4[q], bv = Bb4[q];
        float w0 = __expf((mnv - (av.x+bv.x)) * INVG);
        float w1 = __expf((mnv - (av.y+bv.y)) * INVG);
        float w2 = __expf((mnv - (av.z+bv.z)) * INVG);
        float w3 = __expf((mnv - (av.w+bv.w)) * INVG);
        num += w0 * (float)(4*q+0); den += w0;
        num += w1 * (float)(4*q+1); den += w1;
        num += w2 * (float)(4*q+2); den += w2;
        num += w3 * (float)(4*q+3); den += w3;
      }
      out[b*MW + m] = lbw[m] + (ubw[m] - lbw[m]) * (num/den) * (1.0f/95.0f);
    }
  }
}

extern "C" void kernel_launch(void* const* d_in, const int* in_sizes, int n_in,
                              void* d_out, int out_size, void* d_ws, size_t ws_size,
                              hipStream_t stream) {
  const float* s1f    = (const float*)d_in[0];
  const float* s2f    = (const float*)d_in[1];
  const float* regw   = (const float*)d_in[2];
  const float* glb_lb = (const float*)d_in[3];
  const float* glb_ub = (const float*)d_in[4];
  const float* gubp   = (const float*)d_in[5];
  const float* t1     = (const float*)d_in[6];
  const float* t2     = (const float*)d_in[7];
  const float* twp    = (const float*)d_in[8];
  float* ws  = (float*)d_ws;
  float* out = (float*)d_out;

  // k1: 1D grid of 512, XCD-aware (b,mb) derived in-kernel so that all 16
  // producers of batch b share XCD b%8 = k2 block b's XCD (round-robin).
  k1_node<<<512, 256, 0, stream>>>(s1f, s2f, twp, glb_lb, glb_ub, t1, t2, ws);
  k2_out<<<NB, 512, 0, stream>>>(twp, glb_lb, glb_ub, regw, gubp, t2, ws, out);
}